// Round 2
// baseline (1032.023 us; speedup 1.0000x reference)
//
#include <hip/hip_runtime.h>
#include <hip/hip_bf16.h>

#define TN 131072      // total nodes (B*N)
#define NB 256         // batches
#define NN 512         // nodes per batch
#define FD 128         // per-layer feature dim
#define DD 512         // concat dim
#define NE 2097152     // edges
#define NL 4           // layers

typedef __attribute__((ext_vector_type(8))) short bf16x8;
typedef __attribute__((ext_vector_type(4))) float f32x4;

__device__ __forceinline__ float b2f(unsigned int u) {
    union { unsigned int i; float f; } c; c.i = u << 16; return c.f;
}
__device__ __forceinline__ unsigned short f2b(float f) {
    union { float f; unsigned int i; } c; c.f = f;
    unsigned int x = c.i;
    return (unsigned short)((x + 0x7fffu + ((x >> 16) & 1u)) >> 16);  // RNE
}

// ---------------- CSR build ----------------
__global__ void count_k(const int* __restrict__ dst, int* __restrict__ counts) {
    int e = blockIdx.x * blockDim.x + threadIdx.x;
    if (e < NE) atomicAdd(&counts[dst[e]], 1);
}

__global__ void scan_k(const int* __restrict__ counts, int* __restrict__ row_ptr,
                       int* __restrict__ cursor, float* __restrict__ degs) {
    __shared__ int ssum[1024];
    int t = threadIdx.x;
    const int CH = TN / 1024;  // 128
    int base = t * CH;
    int s = 0;
    for (int i = 0; i < CH; i++) s += counts[base + i];
    ssum[t] = s;
    __syncthreads();
    for (int off = 1; off < 1024; off <<= 1) {
        int v = (t >= off) ? ssum[t - off] : 0;
        __syncthreads();
        ssum[t] += v;
        __syncthreads();
    }
    int prefix = (t == 0) ? 0 : ssum[t - 1];
    for (int i = 0; i < CH; i++) {
        int c = counts[base + i];
        row_ptr[base + i] = prefix;
        cursor[base + i]  = prefix;
        degs[base + i]    = (float)(c + 1);
        prefix += c;
    }
    if (t == 1023) row_ptr[TN] = prefix;
}

__global__ void fill_k(const int* __restrict__ src, const int* __restrict__ dst,
                       int* __restrict__ cursor, int* __restrict__ col_idx) {
    int e = blockIdx.x * blockDim.x + threadIdx.x;
    if (e < NE) {
        int p = atomicAdd(&cursor[dst[e]], 1);
        col_idx[p] = src[e];
    }
}

// ---------------- att_W transpose + bf16 cast:  Wt[n][k] = bf16(W[k][n]) ----------------
__global__ __launch_bounds__(256) void transpose_cast_k(const float* __restrict__ W,
                                                        unsigned short* __restrict__ Wt) {
    __shared__ float tile[32][33];
    int k0 = blockIdx.x * 32, n0 = blockIdx.y * 32;
    int tx = threadIdx.x & 31, ty = threadIdx.x >> 5;  // 32 x 8
    #pragma unroll
    for (int i = 0; i < 32; i += 8)
        tile[ty + i][tx] = W[(size_t)(k0 + ty + i) * DD + n0 + tx];
    __syncthreads();
    #pragma unroll
    for (int i = 0; i < 32; i += 8)
        Wt[(size_t)(n0 + ty + i) * DD + k0 + tx] = f2b(tile[tx][ty + i]);
}

// ---------------- fused conv layer (fp32 compute, bf16 or fp32 in, bf16 out) ----------------
// 64 nodes/block, 256 threads. agg in LDS, W chunked 2x64 cols in LDS.
template <bool BF16IN>
__global__ __launch_bounds__(256) void conv_k(
    const void* __restrict__ h_in_, int hs,
    const float* __restrict__ W, const float* __restrict__ bias,
    const int* __restrict__ rp, const int* __restrict__ ci,
    const float* __restrict__ degs,
    unsigned short* __restrict__ out, int os)
{
    __shared__ float sA[64][132];   // [node][k], +4 pad
    __shared__ float sW[128][68];   // [k][c-chunk], +4 pad
    int tid = threadIdx.x;
    int n0g = blockIdx.x * 64;

    // aggregation: 4 threads/node, 32 feats each
    {
        int nl = tid >> 2;
        int fc = (tid & 3) << 5;
        int g = n0g + nl;
        float acc[32];
        if (BF16IN) {
            const unsigned short* hr = (const unsigned short*)h_in_ + (size_t)g * hs + fc;
            #pragma unroll
            for (int c = 0; c < 4; c++) {
                uint4 v = *(const uint4*)(hr + c * 8);
                acc[c*8+0] = b2f(v.x & 0xffff); acc[c*8+1] = b2f(v.x >> 16);
                acc[c*8+2] = b2f(v.y & 0xffff); acc[c*8+3] = b2f(v.y >> 16);
                acc[c*8+4] = b2f(v.z & 0xffff); acc[c*8+5] = b2f(v.z >> 16);
                acc[c*8+6] = b2f(v.w & 0xffff); acc[c*8+7] = b2f(v.w >> 16);
            }
        } else {
            const float* hr = (const float*)h_in_ + (size_t)g * hs + fc;
            #pragma unroll
            for (int c = 0; c < 8; c++) {
                float4 v = *(const float4*)(hr + c * 4);
                acc[c*4+0] = v.x; acc[c*4+1] = v.y; acc[c*4+2] = v.z; acc[c*4+3] = v.w;
            }
        }
        int rs = rp[g], re = rp[g + 1];
        for (int j = rs; j < re; j++) {
            int s = ci[j];
            if (BF16IN) {
                const unsigned short* hn = (const unsigned short*)h_in_ + (size_t)s * hs + fc;
                #pragma unroll
                for (int c = 0; c < 4; c++) {
                    uint4 v = *(const uint4*)(hn + c * 8);
                    acc[c*8+0] += b2f(v.x & 0xffff); acc[c*8+1] += b2f(v.x >> 16);
                    acc[c*8+2] += b2f(v.y & 0xffff); acc[c*8+3] += b2f(v.y >> 16);
                    acc[c*8+4] += b2f(v.z & 0xffff); acc[c*8+5] += b2f(v.z >> 16);
                    acc[c*8+6] += b2f(v.w & 0xffff); acc[c*8+7] += b2f(v.w >> 16);
                }
            } else {
                const float* hn = (const float*)h_in_ + (size_t)s * hs + fc;
                #pragma unroll
                for (int c = 0; c < 8; c++) {
                    float4 v = *(const float4*)(hn + c * 4);
                    acc[c*4+0] += v.x; acc[c*4+1] += v.y; acc[c*4+2] += v.z; acc[c*4+3] += v.w;
                }
            }
        }
        #pragma unroll
        for (int i = 0; i < 32; i += 4)
            *(float4*)&sA[nl][fc + i] = *(float4*)&acc[i];
    }

    int ng = tid >> 4;   // 0..15 -> rows ng*4
    int cg = tid & 15;   // cols cg*4 within chunk
    float rdeg[4];
    #pragma unroll
    for (int r = 0; r < 4; r++) rdeg[r] = 1.0f / degs[n0g + ng * 4 + r];

    for (int cc = 0; cc < 2; cc++) {
        __syncthreads();   // sA ready (cc=0) / previous GEMM done (cc=1)
        #pragma unroll
        for (int i = 0; i < 8; i++) {
            int f = tid + i * 256;          // float4 id in [0,2048)
            int k = f >> 4, c4 = (f & 15) << 2;
            *(float4*)&sW[k][c4] = *(const float4*)&W[k * 128 + cc * 64 + c4];
        }
        __syncthreads();

        float facc[4][4] = {};
        for (int k = 0; k < 128; k += 4) {
            float4 a4[4], w4[4];
            #pragma unroll
            for (int r = 0; r < 4; r++) a4[r] = *(const float4*)&sA[ng * 4 + r][k];
            #pragma unroll
            for (int kk = 0; kk < 4; kk++) w4[kk] = *(const float4*)&sW[k + kk][cg * 4];
            #pragma unroll
            for (int r = 0; r < 4; r++) {
                float ar[4] = {a4[r].x, a4[r].y, a4[r].z, a4[r].w};
                #pragma unroll
                for (int kk = 0; kk < 4; kk++) {
                    facc[r][0] += ar[kk] * w4[kk].x;
                    facc[r][1] += ar[kk] * w4[kk].y;
                    facc[r][2] += ar[kk] * w4[kk].z;
                    facc[r][3] += ar[kk] * w4[kk].w;
                }
            }
        }
        #pragma unroll
        for (int r = 0; r < 4; r++) {
            int gr = n0g + ng * 4 + r;
            unsigned short q0 = f2b(tanhf((facc[r][0] + bias[cc*64 + cg*4 + 0]) * rdeg[r]));
            unsigned short q1 = f2b(tanhf((facc[r][1] + bias[cc*64 + cg*4 + 1]) * rdeg[r]));
            unsigned short q2 = f2b(tanhf((facc[r][2] + bias[cc*64 + cg*4 + 2]) * rdeg[r]));
            unsigned short q3 = f2b(tanhf((facc[r][3] + bias[cc*64 + cg*4 + 3]) * rdeg[r]));
            uint2 pk;
            pk.x = (unsigned int)q0 | ((unsigned int)q1 << 16);
            pk.y = (unsigned int)q2 | ((unsigned int)q3 << 16);
            *(uint2*)&out[(size_t)gr * os + cc * 64 + cg * 4] = pk;
        }
    }
}

// ---------------- attention scores: bf16 MFMA GEMM + fused tanh/dot-v ----------------
// block 128(M) x 128(N), 4 waves (2x2), wave tile 64x64, BK=64.
__global__ __launch_bounds__(256) void scores_k(
    const unsigned short* __restrict__ X,   // [TN][DD] bf16
    const unsigned short* __restrict__ Wt,  // [DD][DD] bf16, (n,k)
    const float* __restrict__ bv, const float* __restrict__ vv,
    float* __restrict__ sp)                 // [TN][8] partials
{
    __shared__ unsigned short sX[128][72];  // +8 bf16 pad (keeps 16B align, uniform banks)
    __shared__ unsigned short sW[128][72];
    int tid = threadIdx.x;
    int lane = tid & 63, wid = tid >> 6;
    int wm = wid >> 1, wn = wid & 1;
    int m0 = blockIdx.x * 128;
    int n0 = blockIdx.y * 128;
    int lr = lane & 15, lh = lane >> 4;

    f32x4 acc[4][4];
    #pragma unroll
    for (int mi = 0; mi < 4; mi++)
        #pragma unroll
        for (int ni = 0; ni < 4; ni++)
            acc[mi][ni] = (f32x4){0.f, 0.f, 0.f, 0.f};

    for (int k0 = 0; k0 < DD; k0 += 64) {
        __syncthreads();
        #pragma unroll
        for (int i = 0; i < 4; i++) {
            int idx = tid + i * 256;
            int row = idx >> 3, ch = idx & 7;
            *(float4*)&sX[row][ch * 8] = *(const float4*)&X[(size_t)(m0 + row) * DD + k0 + ch * 8];
            *(float4*)&sW[row][ch * 8] = *(const float4*)&Wt[(size_t)(n0 + row) * DD + k0 + ch * 8];
        }
        __syncthreads();
        #pragma unroll
        for (int kk = 0; kk < 64; kk += 32) {
            bf16x8 af[4], bfr[4];
            #pragma unroll
            for (int mi = 0; mi < 4; mi++)
                af[mi] = *(const bf16x8*)&sX[wm * 64 + mi * 16 + lr][kk + lh * 8];
            #pragma unroll
            for (int ni = 0; ni < 4; ni++)
                bfr[ni] = *(const bf16x8*)&sW[wn * 64 + ni * 16 + lr][kk + lh * 8];
            #pragma unroll
            for (int mi = 0; mi < 4; mi++)
                #pragma unroll
                for (int ni = 0; ni < 4; ni++)
                    acc[mi][ni] = __builtin_amdgcn_mfma_f32_16x16x32_bf16(
                        af[mi], bfr[ni], acc[mi][ni], 0, 0, 0);
        }
    }

    // epilogue: tanh(acc + b) * v, sum over this wave's 64 cols, reduce 16 lanes
    float vcol[4], bcol[4];
    #pragma unroll
    for (int ni = 0; ni < 4; ni++) {
        int col = n0 + wn * 64 + ni * 16 + lr;
        vcol[ni] = vv[col];
        bcol[ni] = bv[col];
    }
    #pragma unroll
    for (int mi = 0; mi < 4; mi++) {
        #pragma unroll
        for (int r = 0; r < 4; r++) {
            float part = 0.f;
            #pragma unroll
            for (int ni = 0; ni < 4; ni++)
                part += tanhf(acc[mi][ni][r] + bcol[ni]) * vcol[ni];
            part += __shfl_xor(part, 1);
            part += __shfl_xor(part, 2);
            part += __shfl_xor(part, 4);
            part += __shfl_xor(part, 8);
            if (lr == 0) {
                int row = m0 + wm * 64 + mi * 16 + lh * 4 + r;
                sp[(size_t)row * 8 + blockIdx.y * 2 + wn] = part;
            }
        }
    }
}

// ---------------- softmax + pool (one block per batch) ----------------
__global__ __launch_bounds__(256) void pool_k(
    const float* __restrict__ sp, const unsigned short* __restrict__ X,
    float* __restrict__ pooled)
{
    __shared__ float sattn[512];
    __shared__ float wred[8];
    int b = blockIdx.x, t = threadIdx.x;
    float s0, s1;
    {
        const float4* p = (const float4*)&sp[((size_t)b * NN + t) * 8];
        float4 x = p[0], y = p[1];
        s0 = x.x + x.y + x.z + x.w + y.x + y.y + y.z + y.w;
        p = (const float4*)&sp[((size_t)b * NN + 256 + t) * 8];
        x = p[0]; y = p[1];
        s1 = x.x + x.y + x.z + x.w + y.x + y.y + y.z + y.w;
    }
    float m = fmaxf(s0, s1);
    #pragma unroll
    for (int off = 1; off < 64; off <<= 1) m = fmaxf(m, __shfl_xor(m, off));
    int wid = t >> 6, lane = t & 63;
    if (lane == 0) wred[wid] = m;
    __syncthreads();
    m = fmaxf(fmaxf(wred[0], wred[1]), fmaxf(wred[2], wred[3]));
    float e0 = expf(s0 - m), e1 = expf(s1 - m);
    float ssum = e0 + e1;
    #pragma unroll
    for (int off = 1; off < 64; off <<= 1) ssum += __shfl_xor(ssum, off);
    if (lane == 0) wred[4 + wid] = ssum;
    __syncthreads();
    float inv = 1.0f / (wred[4] + wred[5] + wred[6] + wred[7]);
    sattn[t] = e0 * inv;
    sattn[t + 256] = e1 * inv;
    __syncthreads();
    float2 acc = {0.f, 0.f};
    const unsigned short* Xb = X + (size_t)b * NN * DD;
    #pragma unroll 4
    for (int n = 0; n < NN; n++) {
        float a = sattn[n];
        unsigned int px = *(const unsigned int*)&Xb[(size_t)n * DD + t * 2];
        acc.x += a * b2f(px & 0xffff);
        acc.y += a * b2f(px >> 16);
    }
    pooled[b * DD + t * 2 + 0] = acc.x;
    pooled[b * DD + t * 2 + 1] = acc.y;
}

// ---------------- output layer ----------------
__global__ void out_k(const float* __restrict__ pooled, const float* __restrict__ Wo,
                      const float* __restrict__ bo, float* __restrict__ out) {
    int b = blockIdx.x, c = threadIdx.x;  // 128 threads
    float acc = 0.f;
    const float* p = pooled + b * DD;
    for (int k = 0; k < DD; k++) acc += p[k] * Wo[k * 128 + c];
    out[b * 128 + c] = fmaxf(acc + bo[c], 0.f);
}

extern "C" void kernel_launch(void* const* d_in, const int* in_sizes, int n_in,
                              void* d_out, int out_size, void* d_ws, size_t ws_size,
                              hipStream_t stream)
{
    const float* node_feat = (const float*)d_in[0];
    const int*   edge_src  = (const int*)d_in[1];
    const int*   edge_dst  = (const int*)d_in[2];
    const float* conv_W    = (const float*)d_in[3];
    const float* conv_b    = (const float*)d_in[4];
    const float* att_W     = (const float*)d_in[5];
    const float* att_b     = (const float*)d_in[6];
    const float* att_v     = (const float*)d_in[7];
    const float* out_W     = (const float*)d_in[8];
    const float* out_b     = (const float*)d_in[9];
    float* out = (float*)d_out;
    (void)in_sizes; (void)n_in; (void)out_size;

    char* ws = (char*)d_ws;
    size_t off = 0;
    auto alloc = [&](size_t bytes) {
        void* p = ws + off;
        off += (bytes + 255) & ~(size_t)255;
        return p;
    };
    unsigned short* cat   = (unsigned short*)alloc((size_t)TN * DD * 2);  // bf16
    int*   counts  = (int*)alloc((size_t)TN * 4);
    int*   row_ptr = (int*)alloc((size_t)(TN + 1) * 4);
    int*   cursor  = (int*)alloc((size_t)TN * 4);
    int*   col_idx = (int*)alloc((size_t)NE * 4);
    float* degs    = (float*)alloc((size_t)TN * 4);
    float* sp      = (float*)alloc((size_t)TN * 8 * 4);
    unsigned short* attWt = (unsigned short*)alloc((size_t)DD * DD * 2);  // bf16
    float* pooled  = (float*)alloc((size_t)NB * DD * 4);
    if (off > ws_size) return;  // diagnostic: absmax-fail (not crash) => ws too small

    hipMemsetAsync(counts, 0, (size_t)TN * 4, stream);
    count_k<<<NE / 256, 256, 0, stream>>>(edge_dst, counts);
    scan_k<<<1, 1024, 0, stream>>>(counts, row_ptr, cursor, degs);
    fill_k<<<NE / 256, 256, 0, stream>>>(edge_src, edge_dst, cursor, col_idx);
    transpose_cast_k<<<dim3(DD / 32, DD / 32), 256, 0, stream>>>(att_W, attWt);

    for (int l = 0; l < NL; l++) {
        if (l == 0)
            conv_k<false><<<TN / 64, 256, 0, stream>>>(
                (const void*)node_feat, FD, conv_W, conv_b,
                row_ptr, col_idx, degs, cat, DD);
        else
            conv_k<true><<<TN / 64, 256, 0, stream>>>(
                (const void*)(cat + (size_t)(l - 1) * FD), DD,
                conv_W + (size_t)l * FD * FD, conv_b + (size_t)l * FD,
                row_ptr, col_idx, degs, cat + (size_t)l * FD, DD);
    }
    scores_k<<<dim3(TN / 128, DD / 128), 256, 0, stream>>>(cat, attWt, att_b, att_v, sp);
    pool_k<<<NB, 256, 0, stream>>>(sp, cat, pooled);
    out_k<<<NB, 128, 0, stream>>>(pooled, out_W, out_b, out);
}

// Round 3
// 714.131 us; speedup vs baseline: 1.4451x; 1.4451x over previous
//
#include <hip/hip_runtime.h>
#include <hip/hip_bf16.h>

#define TN 131072      // total nodes (B*N)
#define NB 256         // batches
#define NN 512         // nodes per batch
#define FD 128         // per-layer feature dim
#define DD 512         // concat dim
#define NE 2097152     // edges
#define NL 4           // layers

typedef __attribute__((ext_vector_type(8))) short bf16x8;
typedef __attribute__((ext_vector_type(4))) float f32x4;

__device__ __forceinline__ float b2f(unsigned int u) {
    union { unsigned int i; float f; } c; c.i = u << 16; return c.f;
}
__device__ __forceinline__ unsigned short f2b(float f) {
    union { float f; unsigned int i; } c; c.f = f;
    unsigned int x = c.i;
    return (unsigned short)((x + 0x7fffu + ((x >> 16) & 1u)) >> 16);  // RNE
}
__device__ __forceinline__ void add8(float* a, uint4 v) {
    a[0] += b2f(v.x & 0xffff); a[1] += b2f(v.x >> 16);
    a[2] += b2f(v.y & 0xffff); a[3] += b2f(v.y >> 16);
    a[4] += b2f(v.z & 0xffff); a[5] += b2f(v.z >> 16);
    a[6] += b2f(v.w & 0xffff); a[7] += b2f(v.w >> 16);
}
__device__ __forceinline__ void set8(float* a, uint4 v) {
    a[0] = b2f(v.x & 0xffff); a[1] = b2f(v.x >> 16);
    a[2] = b2f(v.y & 0xffff); a[3] = b2f(v.y >> 16);
    a[4] = b2f(v.z & 0xffff); a[5] = b2f(v.z >> 16);
    a[6] = b2f(v.w & 0xffff); a[7] = b2f(v.w >> 16);
}

// ---------------- CSR build ----------------
__global__ void count_k(const int* __restrict__ dst, int* __restrict__ counts) {
    int e = blockIdx.x * blockDim.x + threadIdx.x;
    if (e < NE) atomicAdd(&counts[dst[e]], 1);
}

__global__ void scan_k(const int* __restrict__ counts, int* __restrict__ row_ptr,
                       int* __restrict__ cursor, float* __restrict__ degs) {
    __shared__ int ssum[1024];
    int t = threadIdx.x;
    const int CH = TN / 1024;  // 128
    int base = t * CH;
    int s = 0;
    for (int i = 0; i < CH; i++) s += counts[base + i];
    ssum[t] = s;
    __syncthreads();
    for (int off = 1; off < 1024; off <<= 1) {
        int v = (t >= off) ? ssum[t - off] : 0;
        __syncthreads();
        ssum[t] += v;
        __syncthreads();
    }
    int prefix = (t == 0) ? 0 : ssum[t - 1];
    for (int i = 0; i < CH; i++) {
        int c = counts[base + i];
        row_ptr[base + i] = prefix;
        cursor[base + i]  = prefix;
        degs[base + i]    = (float)(c + 1);
        prefix += c;
    }
    if (t == 1023) row_ptr[TN] = prefix;
}

__global__ void fill_k(const int* __restrict__ src, const int* __restrict__ dst,
                       int* __restrict__ cursor, int* __restrict__ col_idx) {
    int e = blockIdx.x * blockDim.x + threadIdx.x;
    if (e < NE) {
        int p = atomicAdd(&cursor[dst[e]], 1);
        col_idx[p] = src[e];
    }
}

// ---------------- att_W transpose + bf16 cast:  Wt[n][k] = bf16(W[k][n]) ----------------
__global__ __launch_bounds__(256) void transpose_cast_k(const float* __restrict__ W,
                                                        unsigned short* __restrict__ Wt) {
    __shared__ float tile[32][33];
    int k0 = blockIdx.x * 32, n0 = blockIdx.y * 32;
    int tx = threadIdx.x & 31, ty = threadIdx.x >> 5;  // 32 x 8
    #pragma unroll
    for (int i = 0; i < 32; i += 8)
        tile[ty + i][tx] = W[(size_t)(k0 + ty + i) * DD + n0 + tx];
    __syncthreads();
    #pragma unroll
    for (int i = 0; i < 32; i += 8)
        Wt[(size_t)(n0 + ty + i) * DD + k0 + tx] = f2b(tile[tx][ty + i]);
}

// ---------------- conv_W transpose + bf16 cast per layer: Wt_l[o][f] = bf16(W_l[f][o]) ----
__global__ __launch_bounds__(256) void transp_convW_k(const float* __restrict__ W,
                                                      unsigned short* __restrict__ Wt) {
    __shared__ float tile[32][33];
    const float* Wl = W + (size_t)blockIdx.z * FD * FD;
    unsigned short* Wtl = Wt + (size_t)blockIdx.z * FD * FD;
    int f0 = blockIdx.x * 32, o0 = blockIdx.y * 32;
    int tx = threadIdx.x & 31, ty = threadIdx.x >> 5;
    #pragma unroll
    for (int i = 0; i < 32; i += 8)
        tile[ty + i][tx] = Wl[(size_t)(f0 + ty + i) * FD + o0 + tx];
    __syncthreads();
    #pragma unroll
    for (int i = 0; i < 32; i += 8)
        Wtl[(size_t)(o0 + ty + i) * FD + f0 + tx] = f2b(tile[tx][ty + i]);
}

// ---------------- fused conv layer v2: gather -> LDS bf16 -> MFMA GEMM ----------------
// 128 nodes/block, 512 threads (8 waves). XCD-swizzled grid (1024 blocks).
template <bool BF16IN>
__global__ __launch_bounds__(512, 4) void conv_k(
    const void* __restrict__ h_in_, int hs,
    const unsigned short* __restrict__ Wt,   // [128][128] bf16: Wt[out][f]
    const float* __restrict__ bias,
    const int* __restrict__ rp, const int* __restrict__ ci,
    const float* __restrict__ degs,
    unsigned short* __restrict__ cat, int l)
{
    __shared__ unsigned short aggL[128][136];
    __shared__ unsigned short WtL[128][136];
    int tid = threadIdx.x;
    int nwg = gridDim.x;
    int wg = ((blockIdx.x & 7) * (nwg >> 3)) + (blockIdx.x >> 3);  // XCD swizzle (bijective)
    int n0g = wg * 128;

    // stage Wt: 128x128 bf16 = 2048 uint4, 4 per thread
    #pragma unroll
    for (int i = 0; i < 4; i++) {
        int f = tid + i * 512;
        int r = f >> 4, c = (f & 15) << 3;
        *(uint4*)&WtL[r][c] = *(const uint4*)&Wt[(size_t)r * FD + c];
    }

    // gather: 4 threads/node, 32 feats each, 2-neighbor ILP
    {
        int nl = tid >> 2;
        int fcq = (tid & 3) << 5;
        int g = n0g + nl;
        float acc[32];
        if (BF16IN) {
            const unsigned short* base = (const unsigned short*)h_in_;
            const uint4* R = (const uint4*)(base + (size_t)g * hs + fcq);
            uint4 v0 = R[0], v1 = R[1], v2 = R[2], v3 = R[3];
            set8(acc + 0, v0); set8(acc + 8, v1); set8(acc + 16, v2); set8(acc + 24, v3);
            int rs = rp[g], re = rp[g + 1];
            int j = rs;
            for (; j + 2 <= re; j += 2) {
                int sa = ci[j], sb = ci[j + 1];
                const uint4* A = (const uint4*)(base + (size_t)sa * hs + fcq);
                const uint4* B = (const uint4*)(base + (size_t)sb * hs + fcq);
                uint4 a0 = A[0], a1 = A[1], a2 = A[2], a3 = A[3];
                uint4 b0 = B[0], b1 = B[1], b2 = B[2], b3 = B[3];
                add8(acc + 0, a0); add8(acc + 8, a1); add8(acc + 16, a2); add8(acc + 24, a3);
                add8(acc + 0, b0); add8(acc + 8, b1); add8(acc + 16, b2); add8(acc + 24, b3);
            }
            if (j < re) {
                int sa = ci[j];
                const uint4* A = (const uint4*)(base + (size_t)sa * hs + fcq);
                uint4 a0 = A[0], a1 = A[1], a2 = A[2], a3 = A[3];
                add8(acc + 0, a0); add8(acc + 8, a1); add8(acc + 16, a2); add8(acc + 24, a3);
            }
        } else {
            const float* base = (const float*)h_in_;
            const float4* R = (const float4*)(base + (size_t)g * hs + fcq);
            #pragma unroll
            for (int i = 0; i < 8; i++) {
                float4 v = R[i];
                acc[i*4+0] = v.x; acc[i*4+1] = v.y; acc[i*4+2] = v.z; acc[i*4+3] = v.w;
            }
            int rs = rp[g], re = rp[g + 1];
            int j = rs;
            for (; j + 2 <= re; j += 2) {
                int sa = ci[j], sb = ci[j + 1];
                const float4* A = (const float4*)(base + (size_t)sa * hs + fcq);
                const float4* B = (const float4*)(base + (size_t)sb * hs + fcq);
                #pragma unroll
                for (int i = 0; i < 8; i++) {
                    float4 va = A[i], vb = B[i];
                    acc[i*4+0] += va.x + vb.x; acc[i*4+1] += va.y + vb.y;
                    acc[i*4+2] += va.z + vb.z; acc[i*4+3] += va.w + vb.w;
                }
            }
            if (j < re) {
                int sa = ci[j];
                const float4* A = (const float4*)(base + (size_t)sa * hs + fcq);
                #pragma unroll
                for (int i = 0; i < 8; i++) {
                    float4 va = A[i];
                    acc[i*4+0] += va.x; acc[i*4+1] += va.y;
                    acc[i*4+2] += va.z; acc[i*4+3] += va.w;
                }
            }
        }
        // write agg row-chunk to LDS as bf16
        #pragma unroll
        for (int i = 0; i < 4; i++) {
            uint4 pk;
            pk.x = (unsigned int)f2b(acc[i*8+0]) | ((unsigned int)f2b(acc[i*8+1]) << 16);
            pk.y = (unsigned int)f2b(acc[i*8+2]) | ((unsigned int)f2b(acc[i*8+3]) << 16);
            pk.z = (unsigned int)f2b(acc[i*8+4]) | ((unsigned int)f2b(acc[i*8+5]) << 16);
            pk.w = (unsigned int)f2b(acc[i*8+6]) | ((unsigned int)f2b(acc[i*8+7]) << 16);
            *(uint4*)&aggL[nl][fcq + i*8] = pk;
        }
    }
    __syncthreads();

    // GEMM2: lin[out][dst] = Wt . agg^T, 8 waves as 2(m) x 4(n), wave tile 64x32
    int lane = tid & 63, wid = tid >> 6;
    int wm = wid >> 2, wn = wid & 3;
    int lr = lane & 15, lh = lane >> 4;

    f32x4 c2[4][2];
    #pragma unroll
    for (int mi = 0; mi < 4; mi++)
        #pragma unroll
        for (int ni = 0; ni < 2; ni++)
            c2[mi][ni] = (f32x4){0.f, 0.f, 0.f, 0.f};

    #pragma unroll
    for (int kk = 0; kk < 128; kk += 32) {
        bf16x8 af[4], bfr[2];
        #pragma unroll
        for (int mi = 0; mi < 4; mi++)
            af[mi] = *(const bf16x8*)&WtL[wm * 64 + mi * 16 + lr][kk + lh * 8];
        #pragma unroll
        for (int ni = 0; ni < 2; ni++)
            bfr[ni] = *(const bf16x8*)&aggL[wn * 32 + ni * 16 + lr][kk + lh * 8];
        #pragma unroll
        for (int mi = 0; mi < 4; mi++)
            #pragma unroll
            for (int ni = 0; ni < 2; ni++)
                c2[mi][ni] = __builtin_amdgcn_mfma_f32_16x16x32_bf16(
                    af[mi], bfr[ni], c2[mi][ni], 0, 0, 0);
    }

    // epilogue: tanh((lin + b) / deg), write cat[node][l*128 + out]
    float rdeg[2];
    #pragma unroll
    for (int ni = 0; ni < 2; ni++)
        rdeg[ni] = 1.0f / degs[n0g + wn * 32 + ni * 16 + lr];
    #pragma unroll
    for (int mi = 0; mi < 4; mi++) {
        int fo = wm * 64 + mi * 16 + lh * 4;
        float b0 = bias[fo + 0], b1 = bias[fo + 1], b2 = bias[fo + 2], b3 = bias[fo + 3];
        #pragma unroll
        for (int ni = 0; ni < 2; ni++) {
            int node = n0g + wn * 32 + ni * 16 + lr;
            unsigned short q0 = f2b(tanhf((c2[mi][ni][0] + b0) * rdeg[ni]));
            unsigned short q1 = f2b(tanhf((c2[mi][ni][1] + b1) * rdeg[ni]));
            unsigned short q2 = f2b(tanhf((c2[mi][ni][2] + b2) * rdeg[ni]));
            unsigned short q3 = f2b(tanhf((c2[mi][ni][3] + b3) * rdeg[ni]));
            uint2 pk;
            pk.x = (unsigned int)q0 | ((unsigned int)q1 << 16);
            pk.y = (unsigned int)q2 | ((unsigned int)q3 << 16);
            *(uint2*)&cat[(size_t)node * DD + l * FD + fo] = pk;
        }
    }
}

// ---------------- attention scores: bf16 MFMA GEMM + fused tanh/dot-v ----------------
__global__ __launch_bounds__(256) void scores_k(
    const unsigned short* __restrict__ X,   // [TN][DD] bf16
    const unsigned short* __restrict__ Wt,  // [DD][DD] bf16, (n,k)
    const float* __restrict__ bv, const float* __restrict__ vv,
    float* __restrict__ sp)                 // [TN][8] partials
{
    __shared__ unsigned short sX[128][72];
    __shared__ unsigned short sW[128][72];
    int tid = threadIdx.x;
    int lane = tid & 63, wid = tid >> 6;
    int wm = wid >> 1, wn = wid & 1;
    int m0 = blockIdx.x * 128;
    int n0 = blockIdx.y * 128;
    int lr = lane & 15, lh = lane >> 4;

    f32x4 acc[4][4];
    #pragma unroll
    for (int mi = 0; mi < 4; mi++)
        #pragma unroll
        for (int ni = 0; ni < 4; ni++)
            acc[mi][ni] = (f32x4){0.f, 0.f, 0.f, 0.f};

    for (int k0 = 0; k0 < DD; k0 += 64) {
        __syncthreads();
        #pragma unroll
        for (int i = 0; i < 4; i++) {
            int idx = tid + i * 256;
            int row = idx >> 3, ch = idx & 7;
            *(float4*)&sX[row][ch * 8] = *(const float4*)&X[(size_t)(m0 + row) * DD + k0 + ch * 8];
            *(float4*)&sW[row][ch * 8] = *(const float4*)&Wt[(size_t)(n0 + row) * DD + k0 + ch * 8];
        }
        __syncthreads();
        #pragma unroll
        for (int kk = 0; kk < 64; kk += 32) {
            bf16x8 af[4], bfr[4];
            #pragma unroll
            for (int mi = 0; mi < 4; mi++)
                af[mi] = *(const bf16x8*)&sX[wm * 64 + mi * 16 + lr][kk + lh * 8];
            #pragma unroll
            for (int ni = 0; ni < 4; ni++)
                bfr[ni] = *(const bf16x8*)&sW[wn * 64 + ni * 16 + lr][kk + lh * 8];
            #pragma unroll
            for (int mi = 0; mi < 4; mi++)
                #pragma unroll
                for (int ni = 0; ni < 4; ni++)
                    acc[mi][ni] = __builtin_amdgcn_mfma_f32_16x16x32_bf16(
                        af[mi], bfr[ni], acc[mi][ni], 0, 0, 0);
        }
    }

    float vcol[4], bcol[4];
    #pragma unroll
    for (int ni = 0; ni < 4; ni++) {
        int col = n0 + wn * 64 + ni * 16 + lr;
        vcol[ni] = vv[col];
        bcol[ni] = bv[col];
    }
    #pragma unroll
    for (int mi = 0; mi < 4; mi++) {
        #pragma unroll
        for (int r = 0; r < 4; r++) {
            float part = 0.f;
            #pragma unroll
            for (int ni = 0; ni < 4; ni++)
                part += tanhf(acc[mi][ni][r] + bcol[ni]) * vcol[ni];
            part += __shfl_xor(part, 1);
            part += __shfl_xor(part, 2);
            part += __shfl_xor(part, 4);
            part += __shfl_xor(part, 8);
            if (lr == 0) {
                int row = m0 + wm * 64 + mi * 16 + lh * 4 + r;
                sp[(size_t)row * 8 + blockIdx.y * 2 + wn] = part;
            }
        }
    }
}

// ---------------- softmax + pool (one block per batch) ----------------
__global__ __launch_bounds__(256) void pool_k(
    const float* __restrict__ sp, const unsigned short* __restrict__ X,
    float* __restrict__ pooled)
{
    __shared__ float sattn[512];
    __shared__ float wred[8];
    int b = blockIdx.x, t = threadIdx.x;
    float s0, s1;
    {
        const float4* p = (const float4*)&sp[((size_t)b * NN + t) * 8];
        float4 x = p[0], y = p[1];
        s0 = x.x + x.y + x.z + x.w + y.x + y.y + y.z + y.w;
        p = (const float4*)&sp[((size_t)b * NN + 256 + t) * 8];
        x = p[0]; y = p[1];
        s1 = x.x + x.y + x.z + x.w + y.x + y.y + y.z + y.w;
    }
    float m = fmaxf(s0, s1);
    #pragma unroll
    for (int off = 1; off < 64; off <<= 1) m = fmaxf(m, __shfl_xor(m, off));
    int wid = t >> 6, lane = t & 63;
    if (lane == 0) wred[wid] = m;
    __syncthreads();
    m = fmaxf(fmaxf(wred[0], wred[1]), fmaxf(wred[2], wred[3]));
    float e0 = expf(s0 - m), e1 = expf(s1 - m);
    float ssum = e0 + e1;
    #pragma unroll
    for (int off = 1; off < 64; off <<= 1) ssum += __shfl_xor(ssum, off);
    if (lane == 0) wred[4 + wid] = ssum;
    __syncthreads();
    float inv = 1.0f / (wred[4] + wred[5] + wred[6] + wred[7]);
    sattn[t] = e0 * inv;
    sattn[t + 256] = e1 * inv;
    __syncthreads();
    float2 acc = {0.f, 0.f};
    const unsigned short* Xb = X + (size_t)b * NN * DD;
    #pragma unroll 4
    for (int n = 0; n < NN; n++) {
        float a = sattn[n];
        unsigned int px = *(const unsigned int*)&Xb[(size_t)n * DD + t * 2];
        acc.x += a * b2f(px & 0xffff);
        acc.y += a * b2f(px >> 16);
    }
    pooled[b * DD + t * 2 + 0] = acc.x;
    pooled[b * DD + t * 2 + 1] = acc.y;
}

// ---------------- output layer ----------------
__global__ void out_k(const float* __restrict__ pooled, const float* __restrict__ Wo,
                      const float* __restrict__ bo, float* __restrict__ out) {
    int b = blockIdx.x, c = threadIdx.x;  // 128 threads
    float acc = 0.f;
    const float* p = pooled + b * DD;
    for (int k = 0; k < DD; k++) acc += p[k] * Wo[k * 128 + c];
    out[b * 128 + c] = fmaxf(acc + bo[c], 0.f);
}

extern "C" void kernel_launch(void* const* d_in, const int* in_sizes, int n_in,
                              void* d_out, int out_size, void* d_ws, size_t ws_size,
                              hipStream_t stream)
{
    const float* node_feat = (const float*)d_in[0];
    const int*   edge_src  = (const int*)d_in[1];
    const int*   edge_dst  = (const int*)d_in[2];
    const float* conv_W    = (const float*)d_in[3];
    const float* conv_b    = (const float*)d_in[4];
    const float* att_W     = (const float*)d_in[5];
    const float* att_b     = (const float*)d_in[6];
    const float* att_v     = (const float*)d_in[7];
    const float* out_W     = (const float*)d_in[8];
    const float* out_b     = (const float*)d_in[9];
    float* out = (float*)d_out;
    (void)in_sizes; (void)n_in; (void)out_size;

    char* ws = (char*)d_ws;
    size_t off = 0;
    auto alloc = [&](size_t bytes) {
        void* p = ws + off;
        off += (bytes + 255) & ~(size_t)255;
        return p;
    };
    unsigned short* cat   = (unsigned short*)alloc((size_t)TN * DD * 2);  // bf16
    int*   counts  = (int*)alloc((size_t)TN * 4);
    int*   row_ptr = (int*)alloc((size_t)(TN + 1) * 4);
    int*   cursor  = (int*)alloc((size_t)TN * 4);
    int*   col_idx = (int*)alloc((size_t)NE * 4);
    float* degs    = (float*)alloc((size_t)TN * 4);
    float* sp      = (float*)alloc((size_t)TN * 8 * 4);
    unsigned short* attWt = (unsigned short*)alloc((size_t)DD * DD * 2);  // bf16
    unsigned short* convWt = (unsigned short*)alloc((size_t)NL * FD * FD * 2);
    float* pooled  = (float*)alloc((size_t)NB * DD * 4);
    if (off > ws_size) return;  // diagnostic guard

    hipMemsetAsync(counts, 0, (size_t)TN * 4, stream);
    count_k<<<NE / 256, 256, 0, stream>>>(edge_dst, counts);
    scan_k<<<1, 1024, 0, stream>>>(counts, row_ptr, cursor, degs);
    fill_k<<<NE / 256, 256, 0, stream>>>(edge_src, edge_dst, cursor, col_idx);
    transpose_cast_k<<<dim3(DD / 32, DD / 32), 256, 0, stream>>>(att_W, attWt);
    transp_convW_k<<<dim3(FD / 32, FD / 32, NL), 256, 0, stream>>>(conv_W, convWt);

    for (int l = 0; l < NL; l++) {
        if (l == 0)
            conv_k<false><<<TN / 128, 512, 0, stream>>>(
                (const void*)node_feat, FD, convWt, conv_b,
                row_ptr, col_idx, degs, cat, 0);
        else
            conv_k<true><<<TN / 128, 512, 0, stream>>>(
                (const void*)(cat + (size_t)(l - 1) * FD), DD,
                convWt + (size_t)l * FD * FD, conv_b + (size_t)l * FD,
                row_ptr, col_idx, degs, cat, l);
    }
    scores_k<<<dim3(TN / 128, DD / 128), 256, 0, stream>>>(cat, attWt, att_b, att_v, sp);
    pool_k<<<NB, 256, 0, stream>>>(sp, cat, pooled);
    out_k<<<NB, 128, 0, stream>>>(pooled, out_W, out_b, out);
}

// Round 4
// 614.938 us; speedup vs baseline: 1.6783x; 1.1613x over previous
//
#include <hip/hip_runtime.h>
#include <hip/hip_bf16.h>

#define TN 131072      // total nodes (B*N)
#define NB 256         // batches
#define NN 512         // nodes per batch
#define FD 128         // per-layer feature dim
#define DD 512         // concat dim
#define NE 2097152     // edges
#define NL 4           // layers

typedef __attribute__((ext_vector_type(8))) short bf16x8;
typedef __attribute__((ext_vector_type(4))) float f32x4;

__device__ __forceinline__ float b2f(unsigned int u) {
    union { unsigned int i; float f; } c; c.i = u << 16; return c.f;
}
__device__ __forceinline__ unsigned short f2b(float f) {
    union { float f; unsigned int i; } c; c.f = f;
    unsigned int x = c.i;
    return (unsigned short)((x + 0x7fffu + ((x >> 16) & 1u)) >> 16);  // RNE
}
__device__ __forceinline__ void addv8(float* a, bf16x8 v) {
    #pragma unroll
    for (int e = 0; e < 8; e++)
        a[e] += b2f((unsigned int)(unsigned short)v[e]);
}
__device__ __forceinline__ uint4 packv8(const float* a) {
    uint4 p;
    p.x = (unsigned int)f2b(a[0]) | ((unsigned int)f2b(a[1]) << 16);
    p.y = (unsigned int)f2b(a[2]) | ((unsigned int)f2b(a[3]) << 16);
    p.z = (unsigned int)f2b(a[4]) | ((unsigned int)f2b(a[5]) << 16);
    p.w = (unsigned int)f2b(a[6]) | ((unsigned int)f2b(a[7]) << 16);
    return p;
}

// ---------------- CSR build ----------------
__global__ void count_k(const int* __restrict__ dst, int* __restrict__ counts) {
    int e = blockIdx.x * blockDim.x + threadIdx.x;
    if (e < NE) atomicAdd(&counts[dst[e]], 1);
}

__global__ void scan_k(const int* __restrict__ counts, int* __restrict__ row_ptr,
                       int* __restrict__ cursor, float* __restrict__ degs) {
    __shared__ int ssum[1024];
    int t = threadIdx.x;
    const int CH = TN / 1024;  // 128
    int base = t * CH;
    int s = 0;
    for (int i = 0; i < CH; i++) s += counts[base + i];
    ssum[t] = s;
    __syncthreads();
    for (int off = 1; off < 1024; off <<= 1) {
        int v = (t >= off) ? ssum[t - off] : 0;
        __syncthreads();
        ssum[t] += v;
        __syncthreads();
    }
    int prefix = (t == 0) ? 0 : ssum[t - 1];
    for (int i = 0; i < CH; i++) {
        int c = counts[base + i];
        row_ptr[base + i] = prefix;
        cursor[base + i]  = prefix;
        degs[base + i]    = (float)(c + 1);
        prefix += c;
    }
    if (t == 1023) row_ptr[TN] = prefix;
}

__global__ void fill_k(const int* __restrict__ src, const int* __restrict__ dst,
                       int* __restrict__ cursor, int* __restrict__ col_idx) {
    int e = blockIdx.x * blockDim.x + threadIdx.x;
    if (e < NE) {
        int p = atomicAdd(&cursor[dst[e]], 1);
        col_idx[p] = src[e];
    }
}

// ---------------- att_W transpose + bf16 cast:  Wt[n][k] = bf16(W[k][n]) ----------------
__global__ __launch_bounds__(256) void transpose_cast_k(const float* __restrict__ W,
                                                        unsigned short* __restrict__ Wt) {
    __shared__ float tile[32][33];
    int k0 = blockIdx.x * 32, n0 = blockIdx.y * 32;
    int tx = threadIdx.x & 31, ty = threadIdx.x >> 5;  // 32 x 8
    #pragma unroll
    for (int i = 0; i < 32; i += 8)
        tile[ty + i][tx] = W[(size_t)(k0 + ty + i) * DD + n0 + tx];
    __syncthreads();
    #pragma unroll
    for (int i = 0; i < 32; i += 8)
        Wt[(size_t)(n0 + ty + i) * DD + k0 + tx] = f2b(tile[tx][ty + i]);
}

// ---------------- conv_W transpose + bf16 cast per layer: Wt_l[o][f] = bf16(W_l[f][o]) ----
__global__ __launch_bounds__(256) void transp_convW_k(const float* __restrict__ W,
                                                      unsigned short* __restrict__ Wt) {
    __shared__ float tile[32][33];
    const float* Wl = W + (size_t)blockIdx.z * FD * FD;
    unsigned short* Wtl = Wt + (size_t)blockIdx.z * FD * FD;
    int f0 = blockIdx.x * 32, o0 = blockIdx.y * 32;
    int tx = threadIdx.x & 31, ty = threadIdx.x >> 5;
    #pragma unroll
    for (int i = 0; i < 32; i += 8)
        tile[ty + i][tx] = Wl[(size_t)(f0 + ty + i) * FD + o0 + tx];
    __syncthreads();
    #pragma unroll
    for (int i = 0; i < 32; i += 8)
        Wtl[(size_t)(o0 + ty + i) * FD + f0 + tx] = f2b(tile[tx][ty + i]);
}

// ---------------- fused all-layer conv: one block per batch ----------------
// 512 threads, 8 waves. LDS: full batch feature window (512x128 bf16, XOR-swizzled
// 16B units) + 64-node agg/output tile. Gather from LDS, MFMA vs reg-held Wt frags.
__global__ __launch_bounds__(512, 2) void conv_all_k(
    const float* __restrict__ node_feat,      // [TN][FD] fp32
    const unsigned short* __restrict__ Wt,    // [NL*FD][FD] bf16 (out,f)
    const float* __restrict__ bias,           // [NL*FD]
    const int* __restrict__ rp, const int* __restrict__ ci,
    const float* __restrict__ degs,
    unsigned short* __restrict__ cat)         // [TN][DD] bf16
{
    __shared__ unsigned short hW[NN * FD];    // 128 KB
    __shared__ unsigned short agg[64 * FD];   // 16 KB
    const int tid = threadIdx.x;
    const int g0 = blockIdx.x * NN;

    // initial stage: node_feat fp32 -> hW bf16 (swizzled)
    #pragma unroll
    for (int i = 0; i < 16; i++) {
        int u = tid + i * 512;
        int row = u >> 4, cu = u & 15;
        const float4* s4 = (const float4*)(node_feat + (size_t)(g0 + row) * FD + cu * 8);
        float4 x = s4[0], y = s4[1];
        float tmp[8] = {x.x, x.y, x.z, x.w, y.x, y.y, y.z, y.w};
        *(uint4*)&hW[row * FD + ((cu ^ (row & 7)) << 3)] = packv8(tmp);
    }
    __syncthreads();

    const int lane = tid & 63, wid = tid >> 6;
    const int wm = wid >> 1, wn = wid & 1;     // 4(m) x 2(n) waves
    const int lr = lane & 15, lh = lane >> 4;

    for (int l = 0; l < NL; l++) {
        // B-fragments (Wt rows = output cols) held in registers for the whole layer
        bf16x8 bfr[4][4];  // [ni][ks]
        #pragma unroll
        for (int ni = 0; ni < 4; ni++)
            #pragma unroll
            for (int ks = 0; ks < 4; ks++)
                bfr[ni][ks] = *(const bf16x8*)&Wt[((size_t)l * FD + wn * 64 + ni * 16 + lr) * FD + ks * 32 + lh * 8];

        for (int ch = 0; ch < 8; ch++) {
            // ---- gather: 8 threads/node, 16 feats each, from LDS window ----
            int nloc = ch * 64 + (tid >> 3);
            int sg = tid & 7;
            int u0 = 2 * sg, u1 = 2 * sg + 1;
            float acc[16];
            {
                bf16x8 v0 = *(const bf16x8*)&hW[nloc * FD + ((u0 ^ (nloc & 7)) << 3)];
                bf16x8 v1 = *(const bf16x8*)&hW[nloc * FD + ((u1 ^ (nloc & 7)) << 3)];
                #pragma unroll
                for (int e = 0; e < 8; e++) acc[e] = b2f((unsigned int)(unsigned short)v0[e]);
                #pragma unroll
                for (int e = 0; e < 8; e++) acc[8 + e] = b2f((unsigned int)(unsigned short)v1[e]);
            }
            int gnode = g0 + nloc;
            int rs = rp[gnode], re = rp[gnode + 1];
            int j = rs;
            for (; j + 2 <= re; j += 2) {
                int a1 = ci[j] - g0, a2 = ci[j + 1] - g0;
                bf16x8 p0 = *(const bf16x8*)&hW[a1 * FD + ((u0 ^ (a1 & 7)) << 3)];
                bf16x8 p1 = *(const bf16x8*)&hW[a1 * FD + ((u1 ^ (a1 & 7)) << 3)];
                bf16x8 q0 = *(const bf16x8*)&hW[a2 * FD + ((u0 ^ (a2 & 7)) << 3)];
                bf16x8 q1 = *(const bf16x8*)&hW[a2 * FD + ((u1 ^ (a2 & 7)) << 3)];
                addv8(acc, p0); addv8(acc + 8, p1);
                addv8(acc, q0); addv8(acc + 8, q1);
            }
            if (j < re) {
                int a1 = ci[j] - g0;
                bf16x8 p0 = *(const bf16x8*)&hW[a1 * FD + ((u0 ^ (a1 & 7)) << 3)];
                bf16x8 p1 = *(const bf16x8*)&hW[a1 * FD + ((u1 ^ (a1 & 7)) << 3)];
                addv8(acc, p0); addv8(acc + 8, p1);
            }
            // pack agg row (bf16, swizzled)
            int ar = tid >> 3;
            *(uint4*)&agg[ar * FD + ((u0 ^ (ar & 7)) << 3)] = packv8(acc);
            *(uint4*)&agg[ar * FD + ((u1 ^ (ar & 7)) << 3)] = packv8(acc + 8);
            __syncthreads();

            // ---- MFMA: M=64(dst) x N=128(out), K=128 ----
            f32x4 cacc[4];
            #pragma unroll
            for (int ni = 0; ni < 4; ni++) cacc[ni] = (f32x4){0.f, 0.f, 0.f, 0.f};
            {
                int arow = wm * 16 + lr;
                int rsw = arow & 7;
                #pragma unroll
                for (int ks = 0; ks < 4; ks++) {
                    bf16x8 af = *(const bf16x8*)&agg[arow * FD + (((ks * 4 + lh) ^ rsw) << 3)];
                    #pragma unroll
                    for (int ni = 0; ni < 4; ni++)
                        cacc[ni] = __builtin_amdgcn_mfma_f32_16x16x32_bf16(af, bfr[ni][ks], cacc[ni], 0, 0, 0);
                }
            }
            __syncthreads();   // all A-frag reads done before overwriting agg

            // ---- epilogue: tanh((lin+b)*rdeg) -> agg (reused as output tile) ----
            {
                int drow = wm * 16 + lh * 4;
                float rd[4];
                #pragma unroll
                for (int r = 0; r < 4; r++) rd[r] = 1.0f / degs[g0 + ch * 64 + drow + r];
                #pragma unroll
                for (int ni = 0; ni < 4; ni++) {
                    int col = wn * 64 + ni * 16 + lr;
                    float bc = bias[l * FD + col];
                    int cu2 = col >> 3, cl = col & 7;
                    #pragma unroll
                    for (int r = 0; r < 4; r++) {
                        float v = tanhf((cacc[ni][r] + bc) * rd[r]);
                        int row2 = drow + r;
                        agg[row2 * FD + ((cu2 ^ (row2 & 7)) << 3) + cl] = f2b(v);
                    }
                }
            }
            __syncthreads();

            // ---- flush output tile -> cat (coalesced) ----
            {
                int row = tid >> 3, sg2 = tid & 7;
                int w0 = 2 * sg2, w1 = 2 * sg2 + 1;
                uint4 q0 = *(const uint4*)&agg[row * FD + ((w0 ^ (row & 7)) << 3)];
                uint4 q1 = *(const uint4*)&agg[row * FD + ((w1 ^ (row & 7)) << 3)];
                unsigned short* dstp = &cat[(size_t)(g0 + ch * 64 + row) * DD + l * FD + sg2 * 16];
                *(uint4*)(dstp) = q0;
                *(uint4*)(dstp + 8) = q1;
            }
            __syncthreads();   // protect agg from next chunk's pack
        }

        // re-stage hW with this layer's output (input of layer l+1), from L2-hot cat
        if (l < NL - 1) {
            #pragma unroll
            for (int i = 0; i < 16; i++) {
                int u = tid + i * 512;
                int row = u >> 4, cu = u & 15;
                uint4 v = *(const uint4*)&cat[(size_t)(g0 + row) * DD + l * FD + cu * 8];
                *(uint4*)&hW[row * FD + ((cu ^ (row & 7)) << 3)] = v;
            }
            __syncthreads();
        }
    }
}

// ---------------- attention scores: bf16 MFMA GEMM + fused tanh/dot-v ----------------
__global__ __launch_bounds__(256) void scores_k(
    const unsigned short* __restrict__ X,   // [TN][DD] bf16
    const unsigned short* __restrict__ Wt,  // [DD][DD] bf16, (n,k)
    const float* __restrict__ bv, const float* __restrict__ vv,
    float* __restrict__ sp)                 // [TN][8] partials
{
    __shared__ unsigned short sX[128][72];
    __shared__ unsigned short sW[128][72];
    int tid = threadIdx.x;
    int lane = tid & 63, wid = tid >> 6;
    int wm = wid >> 1, wn = wid & 1;
    int m0 = blockIdx.x * 128;
    int n0 = blockIdx.y * 128;
    int lr = lane & 15, lh = lane >> 4;

    f32x4 acc[4][4];
    #pragma unroll
    for (int mi = 0; mi < 4; mi++)
        #pragma unroll
        for (int ni = 0; ni < 4; ni++)
            acc[mi][ni] = (f32x4){0.f, 0.f, 0.f, 0.f};

    for (int k0 = 0; k0 < DD; k0 += 64) {
        __syncthreads();
        #pragma unroll
        for (int i = 0; i < 4; i++) {
            int idx = tid + i * 256;
            int row = idx >> 3, ch = idx & 7;
            *(float4*)&sX[row][ch * 8] = *(const float4*)&X[(size_t)(m0 + row) * DD + k0 + ch * 8];
            *(float4*)&sW[row][ch * 8] = *(const float4*)&Wt[(size_t)(n0 + row) * DD + k0 + ch * 8];
        }
        __syncthreads();
        #pragma unroll
        for (int kk = 0; kk < 64; kk += 32) {
            bf16x8 af[4], bfr[4];
            #pragma unroll
            for (int mi = 0; mi < 4; mi++)
                af[mi] = *(const bf16x8*)&sX[wm * 64 + mi * 16 + lr][kk + lh * 8];
            #pragma unroll
            for (int ni = 0; ni < 4; ni++)
                bfr[ni] = *(const bf16x8*)&sW[wn * 64 + ni * 16 + lr][kk + lh * 8];
            #pragma unroll
            for (int mi = 0; mi < 4; mi++)
                #pragma unroll
                for (int ni = 0; ni < 4; ni++)
                    acc[mi][ni] = __builtin_amdgcn_mfma_f32_16x16x32_bf16(
                        af[mi], bfr[ni], acc[mi][ni], 0, 0, 0);
        }
    }

    float vcol[4], bcol[4];
    #pragma unroll
    for (int ni = 0; ni < 4; ni++) {
        int col = n0 + wn * 64 + ni * 16 + lr;
        vcol[ni] = vv[col];
        bcol[ni] = bv[col];
    }
    #pragma unroll
    for (int mi = 0; mi < 4; mi++) {
        #pragma unroll
        for (int r = 0; r < 4; r++) {
            float part = 0.f;
            #pragma unroll
            for (int ni = 0; ni < 4; ni++)
                part += tanhf(acc[mi][ni][r] + bcol[ni]) * vcol[ni];
            part += __shfl_xor(part, 1);
            part += __shfl_xor(part, 2);
            part += __shfl_xor(part, 4);
            part += __shfl_xor(part, 8);
            if (lr == 0) {
                int row = m0 + wm * 64 + mi * 16 + lh * 4 + r;
                sp[(size_t)row * 8 + blockIdx.y * 2 + wn] = part;
            }
        }
    }
}

// ---------------- softmax + pool (one block per batch) ----------------
__global__ __launch_bounds__(256) void pool_k(
    const float* __restrict__ sp, const unsigned short* __restrict__ X,
    float* __restrict__ pooled)
{
    __shared__ float sattn[512];
    __shared__ float wred[8];
    int b = blockIdx.x, t = threadIdx.x;
    float s0, s1;
    {
        const float4* p = (const float4*)&sp[((size_t)b * NN + t) * 8];
        float4 x = p[0], y = p[1];
        s0 = x.x + x.y + x.z + x.w + y.x + y.y + y.z + y.w;
        p = (const float4*)&sp[((size_t)b * NN + 256 + t) * 8];
        x = p[0]; y = p[1];
        s1 = x.x + x.y + x.z + x.w + y.x + y.y + y.z + y.w;
    }
    float m = fmaxf(s0, s1);
    #pragma unroll
    for (int off = 1; off < 64; off <<= 1) m = fmaxf(m, __shfl_xor(m, off));
    int wid = t >> 6, lane = t & 63;
    if (lane == 0) wred[wid] = m;
    __syncthreads();
    m = fmaxf(fmaxf(wred[0], wred[1]), fmaxf(wred[2], wred[3]));
    float e0 = expf(s0 - m), e1 = expf(s1 - m);
    float ssum = e0 + e1;
    #pragma unroll
    for (int off = 1; off < 64; off <<= 1) ssum += __shfl_xor(ssum, off);
    if (lane == 0) wred[4 + wid] = ssum;
    __syncthreads();
    float inv = 1.0f / (wred[4] + wred[5] + wred[6] + wred[7]);
    sattn[t] = e0 * inv;
    sattn[t + 256] = e1 * inv;
    __syncthreads();
    float2 acc = {0.f, 0.f};
    const unsigned short* Xb = X + (size_t)b * NN * DD;
    #pragma unroll 4
    for (int n = 0; n < NN; n++) {
        float a = sattn[n];
        unsigned int px = *(const unsigned int*)&Xb[(size_t)n * DD + t * 2];
        acc.x += a * b2f(px & 0xffff);
        acc.y += a * b2f(px >> 16);
    }
    pooled[b * DD + t * 2 + 0] = acc.x;
    pooled[b * DD + t * 2 + 1] = acc.y;
}

// ---------------- output layer ----------------
__global__ void out_k(const float* __restrict__ pooled, const float* __restrict__ Wo,
                      const float* __restrict__ bo, float* __restrict__ out) {
    int b = blockIdx.x, c = threadIdx.x;  // 128 threads
    float acc = 0.f;
    const float* p = pooled + b * DD;
    for (int k = 0; k < DD; k++) acc += p[k] * Wo[k * 128 + c];
    out[b * 128 + c] = fmaxf(acc + bo[c], 0.f);
}

extern "C" void kernel_launch(void* const* d_in, const int* in_sizes, int n_in,
                              void* d_out, int out_size, void* d_ws, size_t ws_size,
                              hipStream_t stream)
{
    const float* node_feat = (const float*)d_in[0];
    const int*   edge_src  = (const int*)d_in[1];
    const int*   edge_dst  = (const int*)d_in[2];
    const float* conv_W    = (const float*)d_in[3];
    const float* conv_b    = (const float*)d_in[4];
    const float* att_W     = (const float*)d_in[5];
    const float* att_b     = (const float*)d_in[6];
    const float* att_v     = (const float*)d_in[7];
    const float* out_W     = (const float*)d_in[8];
    const float* out_b     = (const float*)d_in[9];
    float* out = (float*)d_out;
    (void)in_sizes; (void)n_in; (void)out_size;

    char* ws = (char*)d_ws;
    size_t off = 0;
    auto alloc = [&](size_t bytes) {
        void* p = ws + off;
        off += (bytes + 255) & ~(size_t)255;
        return p;
    };
    unsigned short* cat   = (unsigned short*)alloc((size_t)TN * DD * 2);  // bf16
    int*   counts  = (int*)alloc((size_t)TN * 4);
    int*   row_ptr = (int*)alloc((size_t)(TN + 1) * 4);
    int*   cursor  = (int*)alloc((size_t)TN * 4);
    int*   col_idx = (int*)alloc((size_t)NE * 4);
    float* degs    = (float*)alloc((size_t)TN * 4);
    float* sp      = (float*)alloc((size_t)TN * 8 * 4);
    unsigned short* attWt = (unsigned short*)alloc((size_t)DD * DD * 2);  // bf16
    unsigned short* convWt = (unsigned short*)alloc((size_t)NL * FD * FD * 2);
    float* pooled  = (float*)alloc((size_t)NB * DD * 4);
    if (off > ws_size) return;  // diagnostic guard

    hipMemsetAsync(counts, 0, (size_t)TN * 4, stream);
    count_k<<<NE / 256, 256, 0, stream>>>(edge_dst, counts);
    scan_k<<<1, 1024, 0, stream>>>(counts, row_ptr, cursor, degs);
    fill_k<<<NE / 256, 256, 0, stream>>>(edge_src, edge_dst, cursor, col_idx);
    transpose_cast_k<<<dim3(DD / 32, DD / 32), 256, 0, stream>>>(att_W, attWt);
    transp_convW_k<<<dim3(FD / 32, FD / 32, NL), 256, 0, stream>>>(conv_W, convWt);

    conv_all_k<<<NB, 512, 0, stream>>>(node_feat, convWt, conv_b,
                                       row_ptr, col_idx, degs, cat);

    scores_k<<<dim3(TN / 128, DD / 128), 256, 0, stream>>>(cat, attWt, att_b, att_v, sp);
    pool_k<<<NB, 256, 0, stream>>>(sp, cat, pooled);
    out_k<<<NB, 128, 0, stream>>>(pooled, out_W, out_b, out);
}

// Round 5
// 600.215 us; speedup vs baseline: 1.7194x; 1.0245x over previous
//
#include <hip/hip_runtime.h>
#include <hip/hip_bf16.h>

#define TN 131072      // total nodes (B*N)
#define NB 256         // batches
#define NN 512         // nodes per batch
#define FD 128         // per-layer feature dim
#define DD 512         // concat dim
#define NE 2097152     // edges
#define NL 4           // layers
#define PITCH 136      // padded LDS row pitch in bf16 units (272 B)
#define CICAP 1024     // staged edges per chunk

typedef __attribute__((ext_vector_type(8))) short bf16x8;
typedef __attribute__((ext_vector_type(4))) float f32x4;

__device__ __forceinline__ float b2f(unsigned int u) {
    union { unsigned int i; float f; } c; c.i = u << 16; return c.f;
}
__device__ __forceinline__ unsigned short f2b(float f) {
    union { float f; unsigned int i; } c; c.f = f;
    unsigned int x = c.i;
    return (unsigned short)((x + 0x7fffu + ((x >> 16) & 1u)) >> 16);  // RNE
}
__device__ __forceinline__ void add8(float* a, uint4 v) {
    a[0] += b2f(v.x & 0xffff); a[1] += b2f(v.x >> 16);
    a[2] += b2f(v.y & 0xffff); a[3] += b2f(v.y >> 16);
    a[4] += b2f(v.z & 0xffff); a[5] += b2f(v.z >> 16);
    a[6] += b2f(v.w & 0xffff); a[7] += b2f(v.w >> 16);
}
__device__ __forceinline__ void set8(float* a, uint4 v) {
    a[0] = b2f(v.x & 0xffff); a[1] = b2f(v.x >> 16);
    a[2] = b2f(v.y & 0xffff); a[3] = b2f(v.y >> 16);
    a[4] = b2f(v.z & 0xffff); a[5] = b2f(v.z >> 16);
    a[6] = b2f(v.w & 0xffff); a[7] = b2f(v.w >> 16);
}
__device__ __forceinline__ uint4 packv8(const float* a) {
    uint4 p;
    p.x = (unsigned int)f2b(a[0]) | ((unsigned int)f2b(a[1]) << 16);
    p.y = (unsigned int)f2b(a[2]) | ((unsigned int)f2b(a[3]) << 16);
    p.z = (unsigned int)f2b(a[4]) | ((unsigned int)f2b(a[5]) << 16);
    p.w = (unsigned int)f2b(a[6]) | ((unsigned int)f2b(a[7]) << 16);
    return p;
}

// ---------------- CSR build ----------------
__global__ void count_k(const int* __restrict__ dst, int* __restrict__ counts) {
    int e = blockIdx.x * blockDim.x + threadIdx.x;
    if (e < NE) atomicAdd(&counts[dst[e]], 1);
}

__global__ void scan_k(const int* __restrict__ counts, int* __restrict__ row_ptr,
                       int* __restrict__ cursor, float* __restrict__ degs) {
    __shared__ int ssum[1024];
    int t = threadIdx.x;
    const int CH = TN / 1024;  // 128
    int base = t * CH;
    int s = 0;
    for (int i = 0; i < CH; i++) s += counts[base + i];
    ssum[t] = s;
    __syncthreads();
    for (int off = 1; off < 1024; off <<= 1) {
        int v = (t >= off) ? ssum[t - off] : 0;
        __syncthreads();
        ssum[t] += v;
        __syncthreads();
    }
    int prefix = (t == 0) ? 0 : ssum[t - 1];
    for (int i = 0; i < CH; i++) {
        int c = counts[base + i];
        row_ptr[base + i] = prefix;
        cursor[base + i]  = prefix;
        degs[base + i]    = (float)(c + 1);
        prefix += c;
    }
    if (t == 1023) row_ptr[TN] = prefix;
}

__global__ void fill_k(const int* __restrict__ src, const int* __restrict__ dst,
                       int* __restrict__ cursor, int* __restrict__ col_idx) {
    int e = blockIdx.x * blockDim.x + threadIdx.x;
    if (e < NE) {
        int p = atomicAdd(&cursor[dst[e]], 1);
        col_idx[p] = src[e];
    }
}

// ---------------- att_W transpose + bf16 cast:  Wt[n][k] = bf16(W[k][n]) ----------------
__global__ __launch_bounds__(256) void transpose_cast_k(const float* __restrict__ W,
                                                        unsigned short* __restrict__ Wt) {
    __shared__ float tile[32][33];
    int k0 = blockIdx.x * 32, n0 = blockIdx.y * 32;
    int tx = threadIdx.x & 31, ty = threadIdx.x >> 5;  // 32 x 8
    #pragma unroll
    for (int i = 0; i < 32; i += 8)
        tile[ty + i][tx] = W[(size_t)(k0 + ty + i) * DD + n0 + tx];
    __syncthreads();
    #pragma unroll
    for (int i = 0; i < 32; i += 8)
        Wt[(size_t)(n0 + ty + i) * DD + k0 + tx] = f2b(tile[tx][ty + i]);
}

// ---------------- conv_W transpose + bf16 cast per layer: Wt_l[o][f] = bf16(W_l[f][o]) ----
__global__ __launch_bounds__(256) void transp_convW_k(const float* __restrict__ W,
                                                      unsigned short* __restrict__ Wt) {
    __shared__ float tile[32][33];
    const float* Wl = W + (size_t)blockIdx.z * FD * FD;
    unsigned short* Wtl = Wt + (size_t)blockIdx.z * FD * FD;
    int f0 = blockIdx.x * 32, o0 = blockIdx.y * 32;
    int tx = threadIdx.x & 31, ty = threadIdx.x >> 5;
    #pragma unroll
    for (int i = 0; i < 32; i += 8)
        tile[ty + i][tx] = Wl[(size_t)(f0 + ty + i) * FD + o0 + tx];
    __syncthreads();
    #pragma unroll
    for (int i = 0; i < 32; i += 8)
        Wtl[(size_t)(o0 + ty + i) * FD + f0 + tx] = f2b(tile[tx][ty + i]);
}

// ---------------- fused all-layer conv: one block per batch, 1024 threads ----------------
// LDS: 512x128 bf16 window (pitch-136 padded) + 64-node agg tile + staged col_idx.
__global__ __launch_bounds__(1024, 4) void conv_all_k(
    const float* __restrict__ node_feat,      // [TN][FD] fp32
    const unsigned short* __restrict__ Wt,    // [NL*FD][FD] bf16 (out,f)
    const float* __restrict__ bias,           // [NL*FD]
    const int* __restrict__ rp, const int* __restrict__ ci,
    const float* __restrict__ degs,
    unsigned short* __restrict__ cat)         // [TN][DD] bf16
{
    __shared__ unsigned short hW[NN * PITCH];   // 139264 B
    __shared__ unsigned short agg[64 * PITCH];  // 17408 B
    __shared__ int ciL[CICAP];                  // 4096 B
    const int tid = threadIdx.x;
    const int g0 = blockIdx.x * NN;

    // initial stage: node_feat fp32 -> hW bf16 (padded rows)
    #pragma unroll
    for (int i = 0; i < 8; i++) {
        int u = tid + i * 1024;
        int row = u >> 4, cu = u & 15;
        const float4* s4 = (const float4*)(node_feat + (size_t)(g0 + row) * FD + cu * 8);
        float4 x = s4[0], y = s4[1];
        float tmp[8] = {x.x, x.y, x.z, x.w, y.x, y.y, y.z, y.w};
        *(uint4*)&hW[row * PITCH + cu * 8] = packv8(tmp);
    }

    const int lane = tid & 63, wid = tid >> 6;
    const int wm = wid >> 2, wn = wid & 3;     // 4(m) x 4(n) waves
    const int lr = lane & 15, lh = lane >> 4;
    const int gn = tid >> 4;                   // gather: node within chunk (0..63)
    const int ug = tid & 15;                   // gather: 16B unit within row

    for (int l = 0; l < NL; l++) {
        // B-fragments (Wt rows = output cols) in registers for the whole layer
        bf16x8 bfr[2][4];  // [ni][ks]
        #pragma unroll
        for (int ni = 0; ni < 2; ni++)
            #pragma unroll
            for (int ks = 0; ks < 4; ks++)
                bfr[ni][ks] = *(const bf16x8*)&Wt[((size_t)l * FD + wn * 32 + ni * 16 + lr) * FD + ks * 32 + lh * 8];
        __syncthreads();   // hW staged / restaged

        for (int ch = 0; ch < 8; ch++) {
            int crow0 = g0 + ch * 64;
            int ebase = rp[crow0];
            int cnt = rp[crow0 + 64] - ebase;
            if (cnt > CICAP) cnt = CICAP;
            // stage chunk col_idx (pre-localized)
            if (tid < cnt) ciL[tid] = ci[ebase + tid] - g0;
            __syncthreads();   // ciL ready; agg free (prev chunk MFMA reads done)

            // ---- gather: 16 threads/node, 8 feats each, from LDS window ----
            {
                float acc[8];
                set8(acc, *(const uint4*)&hW[(ch * 64 + gn) * PITCH + ug * 8]);
                int gnode = crow0 + gn;
                int rs = rp[gnode], re = rp[gnode + 1];
                int r1 = min(re, ebase + cnt);
                int j = rs;
                for (; j + 4 <= r1; j += 4) {
                    int s0 = ciL[j - ebase], s1 = ciL[j - ebase + 1];
                    int s2 = ciL[j - ebase + 2], s3 = ciL[j - ebase + 3];
                    uint4 w0 = *(const uint4*)&hW[s0 * PITCH + ug * 8];
                    uint4 w1 = *(const uint4*)&hW[s1 * PITCH + ug * 8];
                    uint4 w2 = *(const uint4*)&hW[s2 * PITCH + ug * 8];
                    uint4 w3 = *(const uint4*)&hW[s3 * PITCH + ug * 8];
                    add8(acc, w0); add8(acc, w1); add8(acc, w2); add8(acc, w3);
                }
                for (; j < r1; j++) {
                    int s0 = ciL[j - ebase];
                    add8(acc, *(const uint4*)&hW[s0 * PITCH + ug * 8]);
                }
                for (; j < re; j++) {   // rare overflow tail
                    int s0 = ci[j] - g0;
                    add8(acc, *(const uint4*)&hW[s0 * PITCH + ug * 8]);
                }
                *(uint4*)&agg[gn * PITCH + ug * 8] = packv8(acc);
            }
            __syncthreads();   // agg ready

            // ---- MFMA: M=64(dst) x N=128(out), K=128; wave tile 16x32 ----
            f32x4 cacc[2];
            cacc[0] = (f32x4){0.f, 0.f, 0.f, 0.f};
            cacc[1] = (f32x4){0.f, 0.f, 0.f, 0.f};
            {
                const unsigned short* arow = &agg[(wm * 16 + lr) * PITCH];
                #pragma unroll
                for (int ks = 0; ks < 4; ks++) {
                    bf16x8 af = *(const bf16x8*)&arow[ks * 32 + lh * 8];
                    cacc[0] = __builtin_amdgcn_mfma_f32_16x16x32_bf16(af, bfr[0][ks], cacc[0], 0, 0, 0);
                    cacc[1] = __builtin_amdgcn_mfma_f32_16x16x32_bf16(af, bfr[1][ks], cacc[1], 0, 0, 0);
                }
            }

            // ---- epilogue: tanh((lin+b)*rdeg) -> cat directly ----
            {
                float4 d4 = *(const float4*)&degs[crow0 + wm * 16 + lh * 4];
                float rd[4] = {1.0f / d4.x, 1.0f / d4.y, 1.0f / d4.z, 1.0f / d4.w};
                #pragma unroll
                for (int ni = 0; ni < 2; ni++) {
                    int col = wn * 32 + ni * 16 + lr;
                    float bc = bias[l * FD + col];
                    #pragma unroll
                    for (int r = 0; r < 4; r++) {
                        int grow = crow0 + wm * 16 + lh * 4 + r;
                        cat[(size_t)grow * DD + l * FD + col] =
                            f2b(tanhf((cacc[ni][r] + bc) * rd[r]));
                    }
                }
            }
            // next iteration's first barrier protects agg/ciL reuse
        }

        // restage hW with this layer's output (input of layer l+1) from cat
        if (l < NL - 1) {
            __syncthreads();   // all epilogue stores drained (vmcnt0 before barrier)
            #pragma unroll
            for (int i = 0; i < 8; i++) {
                int u = tid + i * 1024;
                int row = u >> 4, cu = u & 15;
                uint4 v = *(const uint4*)&cat[(size_t)(g0 + row) * DD + l * FD + cu * 8];
                *(uint4*)&hW[row * PITCH + cu * 8] = v;
            }
        }
    }
}

// ---------------- attention scores: bf16 MFMA GEMM + fused tanh/dot-v ----------------
__global__ __launch_bounds__(256) void scores_k(
    const unsigned short* __restrict__ X,   // [TN][DD] bf16
    const unsigned short* __restrict__ Wt,  // [DD][DD] bf16, (n,k)
    const float* __restrict__ bv, const float* __restrict__ vv,
    float* __restrict__ sp)                 // [TN][8] partials
{
    __shared__ unsigned short sX[128][72];
    __shared__ unsigned short sW[128][72];
    int tid = threadIdx.x;
    int lane = tid & 63, wid = tid >> 6;
    int wm = wid >> 1, wn = wid & 1;
    int m0 = blockIdx.x * 128;
    int n0 = blockIdx.y * 128;
    int lr = lane & 15, lh = lane >> 4;

    f32x4 acc[4][4];
    #pragma unroll
    for (int mi = 0; mi < 4; mi++)
        #pragma unroll
        for (int ni = 0; ni < 4; ni++)
            acc[mi][ni] = (f32x4){0.f, 0.f, 0.f, 0.f};

    for (int k0 = 0; k0 < DD; k0 += 64) {
        __syncthreads();
        #pragma unroll
        for (int i = 0; i < 4; i++) {
            int idx = tid + i * 256;
            int row = idx >> 3, ch = idx & 7;
            *(float4*)&sX[row][ch * 8] = *(const float4*)&X[(size_t)(m0 + row) * DD + k0 + ch * 8];
            *(float4*)&sW[row][ch * 8] = *(const float4*)&Wt[(size_t)(n0 + row) * DD + k0 + ch * 8];
        }
        __syncthreads();
        #pragma unroll
        for (int kk = 0; kk < 64; kk += 32) {
            bf16x8 af[4], bfr[4];
            #pragma unroll
            for (int mi = 0; mi < 4; mi++)
                af[mi] = *(const bf16x8*)&sX[wm * 64 + mi * 16 + lr][kk + lh * 8];
            #pragma unroll
            for (int ni = 0; ni < 4; ni++)
                bfr[ni] = *(const bf16x8*)&sW[wn * 64 + ni * 16 + lr][kk + lh * 8];
            #pragma unroll
            for (int mi = 0; mi < 4; mi++)
                #pragma unroll
                for (int ni = 0; ni < 4; ni++)
                    acc[mi][ni] = __builtin_amdgcn_mfma_f32_16x16x32_bf16(
                        af[mi], bfr[ni], acc[mi][ni], 0, 0, 0);
        }
    }

    float vcol[4], bcol[4];
    #pragma unroll
    for (int ni = 0; ni < 4; ni++) {
        int col = n0 + wn * 64 + ni * 16 + lr;
        vcol[ni] = vv[col];
        bcol[ni] = bv[col];
    }
    #pragma unroll
    for (int mi = 0; mi < 4; mi++) {
        #pragma unroll
        for (int r = 0; r < 4; r++) {
            float part = 0.f;
            #pragma unroll
            for (int ni = 0; ni < 4; ni++)
                part += tanhf(acc[mi][ni][r] + bcol[ni]) * vcol[ni];
            part += __shfl_xor(part, 1);
            part += __shfl_xor(part, 2);
            part += __shfl_xor(part, 4);
            part += __shfl_xor(part, 8);
            if (lr == 0) {
                int row = m0 + wm * 64 + mi * 16 + lh * 4 + r;
                sp[(size_t)row * 8 + blockIdx.y * 2 + wn] = part;
            }
        }
    }
}

// ---------------- softmax + pool (one block per batch) ----------------
__global__ __launch_bounds__(256) void pool_k(
    const float* __restrict__ sp, const unsigned short* __restrict__ X,
    float* __restrict__ pooled)
{
    __shared__ float sattn[512];
    __shared__ float wred[8];
    int b = blockIdx.x, t = threadIdx.x;
    float s0, s1;
    {
        const float4* p = (const float4*)&sp[((size_t)b * NN + t) * 8];
        float4 x = p[0], y = p[1];
        s0 = x.x + x.y + x.z + x.w + y.x + y.y + y.z + y.w;
        p = (const float4*)&sp[((size_t)b * NN + 256 + t) * 8];
        x = p[0]; y = p[1];
        s1 = x.x + x.y + x.z + x.w + y.x + y.y + y.z + y.w;
    }
    float m = fmaxf(s0, s1);
    #pragma unroll
    for (int off = 1; off < 64; off <<= 1) m = fmaxf(m, __shfl_xor(m, off));
    int wid = t >> 6, lane = t & 63;
    if (lane == 0) wred[wid] = m;
    __syncthreads();
    m = fmaxf(fmaxf(wred[0], wred[1]), fmaxf(wred[2], wred[3]));
    float e0 = expf(s0 - m), e1 = expf(s1 - m);
    float ssum = e0 + e1;
    #pragma unroll
    for (int off = 1; off < 64; off <<= 1) ssum += __shfl_xor(ssum, off);
    if (lane == 0) wred[4 + wid] = ssum;
    __syncthreads();
    float inv = 1.0f / (wred[4] + wred[5] + wred[6] + wred[7]);
    sattn[t] = e0 * inv;
    sattn[t + 256] = e1 * inv;
    __syncthreads();
    float2 acc = {0.f, 0.f};
    const unsigned short* Xb = X + (size_t)b * NN * DD;
    #pragma unroll 4
    for (int n = 0; n < NN; n++) {
        float a = sattn[n];
        unsigned int px = *(const unsigned int*)&Xb[(size_t)n * DD + t * 2];
        acc.x += a * b2f(px & 0xffff);
        acc.y += a * b2f(px >> 16);
    }
    pooled[b * DD + t * 2 + 0] = acc.x;
    pooled[b * DD + t * 2 + 1] = acc.y;
}

// ---------------- output layer ----------------
__global__ void out_k(const float* __restrict__ pooled, const float* __restrict__ Wo,
                      const float* __restrict__ bo, float* __restrict__ out) {
    int b = blockIdx.x, c = threadIdx.x;  // 128 threads
    float acc = 0.f;
    const float* p = pooled + b * DD;
    for (int k = 0; k < DD; k++) acc += p[k] * Wo[k * 128 + c];
    out[b * 128 + c] = fmaxf(acc + bo[c], 0.f);
}

extern "C" void kernel_launch(void* const* d_in, const int* in_sizes, int n_in,
                              void* d_out, int out_size, void* d_ws, size_t ws_size,
                              hipStream_t stream)
{
    const float* node_feat = (const float*)d_in[0];
    const int*   edge_src  = (const int*)d_in[1];
    const int*   edge_dst  = (const int*)d_in[2];
    const float* conv_W    = (const float*)d_in[3];
    const float* conv_b    = (const float*)d_in[4];
    const float* att_W     = (const float*)d_in[5];
    const float* att_b     = (const float*)d_in[6];
    const float* att_v     = (const float*)d_in[7];
    const float* out_W     = (const float*)d_in[8];
    const float* out_b     = (const float*)d_in[9];
    float* out = (float*)d_out;
    (void)in_sizes; (void)n_in; (void)out_size;

    char* ws = (char*)d_ws;
    size_t off = 0;
    auto alloc = [&](size_t bytes) {
        void* p = ws + off;
        off += (bytes + 255) & ~(size_t)255;
        return p;
    };
    unsigned short* cat   = (unsigned short*)alloc((size_t)TN * DD * 2);  // bf16
    int*   counts  = (int*)alloc((size_t)TN * 4);
    int*   row_ptr = (int*)alloc((size_t)(TN + 1) * 4);
    int*   cursor  = (int*)alloc((size_t)TN * 4);
    int*   col_idx = (int*)alloc((size_t)NE * 4);
    float* degs    = (float*)alloc((size_t)TN * 4);
    float* sp      = (float*)alloc((size_t)TN * 8 * 4);
    unsigned short* attWt = (unsigned short*)alloc((size_t)DD * DD * 2);  // bf16
    unsigned short* convWt = (unsigned short*)alloc((size_t)NL * FD * FD * 2);
    float* pooled  = (float*)alloc((size_t)NB * DD * 4);
    if (off > ws_size) return;  // diagnostic guard

    hipMemsetAsync(counts, 0, (size_t)TN * 4, stream);
    count_k<<<NE / 256, 256, 0, stream>>>(edge_dst, counts);
    scan_k<<<1, 1024, 0, stream>>>(counts, row_ptr, cursor, degs);
    fill_k<<<NE / 256, 256, 0, stream>>>(edge_src, edge_dst, cursor, col_idx);
    transpose_cast_k<<<dim3(DD / 32, DD / 32), 256, 0, stream>>>(att_W, attWt);
    transp_convW_k<<<dim3(FD / 32, FD / 32, NL), 256, 0, stream>>>(conv_W, convWt);

    conv_all_k<<<NB, 1024, 0, stream>>>(node_feat, convWt, conv_b,
                                        row_ptr, col_idx, degs, cat);

    scores_k<<<dim3(TN / 128, DD / 128), 256, 0, stream>>>(cat, attWt, att_b, att_v, sp);
    pool_k<<<NB, 256, 0, stream>>>(sp, cat, pooled);
    out_k<<<NB, 128, 0, stream>>>(pooled, out_W, out_b, out);
}

// Round 6
// 536.174 us; speedup vs baseline: 1.9248x; 1.1194x over previous
//
#include <hip/hip_runtime.h>
#include <hip/hip_bf16.h>

#define TN 131072      // total nodes (B*N)
#define NB 256         // batches
#define NN 512         // nodes per batch
#define FD 128         // per-layer feature dim
#define DD 512         // concat dim
#define NE 2097152     // edges
#define NL 4           // layers
#define PITCH 136      // padded LDS row pitch in bf16 units (272 B)

typedef __attribute__((ext_vector_type(8))) short bf16x8;
typedef __attribute__((ext_vector_type(4))) float f32x4;

__device__ __forceinline__ float b2f(unsigned int u) {
    union { unsigned int i; float f; } c; c.i = u << 16; return c.f;
}
__device__ __forceinline__ unsigned short f2b(float f) {
    union { float f; unsigned int i; } c; c.f = f;
    unsigned int x = c.i;
    return (unsigned short)((x + 0x7fffu + ((x >> 16) & 1u)) >> 16);  // RNE
}
__device__ __forceinline__ void add8(float* a, uint4 v) {
    a[0] += b2f(v.x & 0xffff); a[1] += b2f(v.x >> 16);
    a[2] += b2f(v.y & 0xffff); a[3] += b2f(v.y >> 16);
    a[4] += b2f(v.z & 0xffff); a[5] += b2f(v.z >> 16);
    a[6] += b2f(v.w & 0xffff); a[7] += b2f(v.w >> 16);
}
__device__ __forceinline__ void set8(float* a, uint4 v) {
    a[0] = b2f(v.x & 0xffff); a[1] = b2f(v.x >> 16);
    a[2] = b2f(v.y & 0xffff); a[3] = b2f(v.y >> 16);
    a[4] = b2f(v.z & 0xffff); a[5] = b2f(v.z >> 16);
    a[6] = b2f(v.w & 0xffff); a[7] = b2f(v.w >> 16);
}
__device__ __forceinline__ uint4 packv8(const float* a) {
    uint4 p;
    p.x = (unsigned int)f2b(a[0]) | ((unsigned int)f2b(a[1]) << 16);
    p.y = (unsigned int)f2b(a[2]) | ((unsigned int)f2b(a[3]) << 16);
    p.z = (unsigned int)f2b(a[4]) | ((unsigned int)f2b(a[5]) << 16);
    p.w = (unsigned int)f2b(a[6]) | ((unsigned int)f2b(a[7]) << 16);
    return p;
}
__device__ __forceinline__ bf16x8 packb8(const float* a) {
    union { uint4 u; bf16x8 b; } c;
    c.u = packv8(a);
    return c.b;
}
// fast tanh: (e^{2x}-1)/(e^{2x}+1), clamp so bf16-exact saturation
__device__ __forceinline__ float ftanh(float x) {
    float xc = fminf(fmaxf(x, -9.0f), 9.0f);
    float e = __expf(2.0f * xc);
    return (e - 1.0f) * __builtin_amdgcn_rcpf(e + 1.0f);
}

// ---------------- CSR build ----------------
__global__ void count_k(const int* __restrict__ dst, int* __restrict__ counts) {
    int e = blockIdx.x * blockDim.x + threadIdx.x;
    if (e < NE) atomicAdd(&counts[dst[e]], 1);
}

// per-batch scan: 256 blocks x 512 threads (each batch has exactly NN*DEG=8192 edges)
__global__ __launch_bounds__(512) void scan_b_k(const int* __restrict__ counts,
                                                int* __restrict__ row_ptr,
                                                int* __restrict__ cursor,
                                                float* __restrict__ degs) {
    __shared__ int ss[512];
    int b = blockIdx.x, t = threadIdx.x;
    int gid = b * NN + t;
    int c = counts[gid];
    ss[t] = c;
    __syncthreads();
    for (int off = 1; off < 512; off <<= 1) {
        int v = (t >= off) ? ss[t - off] : 0;
        __syncthreads();
        ss[t] += v;
        __syncthreads();
    }
    int excl = ss[t] - c;
    int base = b * (NN * 16) + excl;   // DEG=16
    row_ptr[gid] = base;
    cursor[gid]  = base;
    degs[gid]    = (float)(c + 1);
    if (b == NB - 1 && t == NN - 1) row_ptr[TN] = NE;
}

__global__ void fill_k(const int* __restrict__ src, const int* __restrict__ dst,
                       int* __restrict__ cursor, int* __restrict__ col_idx) {
    int e = blockIdx.x * blockDim.x + threadIdx.x;
    if (e < NE) {
        int p = atomicAdd(&cursor[dst[e]], 1);
        col_idx[p] = src[e];
    }
}

// ---------------- att_W transpose + bf16 cast:  Wt[n][k] = bf16(W[k][n]) ----------------
__global__ __launch_bounds__(256) void transpose_cast_k(const float* __restrict__ W,
                                                        unsigned short* __restrict__ Wt) {
    __shared__ float tile[32][33];
    int k0 = blockIdx.x * 32, n0 = blockIdx.y * 32;
    int tx = threadIdx.x & 31, ty = threadIdx.x >> 5;  // 32 x 8
    #pragma unroll
    for (int i = 0; i < 32; i += 8)
        tile[ty + i][tx] = W[(size_t)(k0 + ty + i) * DD + n0 + tx];
    __syncthreads();
    #pragma unroll
    for (int i = 0; i < 32; i += 8)
        Wt[(size_t)(n0 + ty + i) * DD + k0 + tx] = f2b(tile[tx][ty + i]);
}

// ---------------- conv_W transpose + bf16 cast per layer: Wt_l[o][f] = bf16(W_l[f][o]) ----
__global__ __launch_bounds__(256) void transp_convW_k(const float* __restrict__ W,
                                                      unsigned short* __restrict__ Wt) {
    __shared__ float tile[32][33];
    const float* Wl = W + (size_t)blockIdx.z * FD * FD;
    unsigned short* Wtl = Wt + (size_t)blockIdx.z * FD * FD;
    int f0 = blockIdx.x * 32, o0 = blockIdx.y * 32;
    int tx = threadIdx.x & 31, ty = threadIdx.x >> 5;
    #pragma unroll
    for (int i = 0; i < 32; i += 8)
        tile[ty + i][tx] = Wl[(size_t)(f0 + ty + i) * FD + o0 + tx];
    __syncthreads();
    #pragma unroll
    for (int i = 0; i < 32; i += 8)
        Wtl[(size_t)(o0 + ty + i) * FD + f0 + tx] = f2b(tile[tx][ty + i]);
}

// ---------------- fused all-layer conv v3: barrier-free per-wave pipeline ----------------
// One block per batch, 1024 threads (16 waves). Window in LDS (padded). Each wave owns
// 32 rows (2 passes x 16): lane (lr,lh) gathers A-frag feats of row (2w+p)*16+lr into
// REGISTERS, MFMAs against global-L2 B-frags, epilogue -> cat. Only 2 barriers/layer.
__global__ __launch_bounds__(1024) void conv_all_k(
    const float* __restrict__ node_feat,      // [TN][FD] fp32
    const unsigned short* __restrict__ Wt,    // [NL*FD][FD] bf16 (out,f)
    const float* __restrict__ bias,           // [NL*FD]
    const int* __restrict__ rp, const int* __restrict__ ci,
    const float* __restrict__ degs,
    unsigned short* __restrict__ cat)         // [TN][DD] bf16
{
    __shared__ unsigned short hW[NN * PITCH];   // 139,264 B
    const int tid = threadIdx.x;
    const int g0 = blockIdx.x * NN;
    const int lane = tid & 63, w = tid >> 6;
    const int lr = lane & 15, lh = lane >> 4;

    // initial stage: node_feat fp32 -> hW bf16 (padded rows)
    #pragma unroll
    for (int i = 0; i < 8; i++) {
        int u = tid + i * 1024;
        int row = u >> 4, cu = u & 15;
        const float4* s4 = (const float4*)(node_feat + (size_t)(g0 + row) * FD + cu * 8);
        float4 x = s4[0], y = s4[1];
        float tmp[8] = {x.x, x.y, x.z, x.w, y.x, y.y, y.z, y.w};
        *(uint4*)&hW[row * PITCH + cu * 8] = packv8(tmp);
    }
    __syncthreads();

    for (int l = 0; l < NL; l++) {
        const unsigned short* Wl = Wt + (size_t)l * FD * FD;
        #pragma unroll
        for (int p = 0; p < 2; p++) {
            const int row_m0 = (w * 2 + p) * 16;   // m-tile base (0..496)
            const int myrow = row_m0 + lr;
            // ---- gather this lane's A-frag feats: f = ks*32 + lh*8 + j ----
            float acc[4][8];
            {
                const unsigned short* hr = &hW[myrow * PITCH + lh * 8];
                #pragma unroll
                for (int ks = 0; ks < 4; ks++)
                    set8(acc[ks], *(const uint4*)&hr[ks * 32]);
            }
            int rs = rp[g0 + myrow], re = rp[g0 + myrow + 1];
            int j = rs;
            for (; j + 2 <= re; j += 2) {
                int s0 = ci[j] - g0, s1 = ci[j + 1] - g0;
                const unsigned short* h0 = &hW[s0 * PITCH + lh * 8];
                const unsigned short* h1 = &hW[s1 * PITCH + lh * 8];
                uint4 a0 = *(const uint4*)&h0[0],  a1 = *(const uint4*)&h0[32];
                uint4 a2 = *(const uint4*)&h0[64], a3 = *(const uint4*)&h0[96];
                uint4 b0 = *(const uint4*)&h1[0],  b1 = *(const uint4*)&h1[32];
                uint4 b2 = *(const uint4*)&h1[64], b3 = *(const uint4*)&h1[96];
                add8(acc[0], a0); add8(acc[1], a1); add8(acc[2], a2); add8(acc[3], a3);
                add8(acc[0], b0); add8(acc[1], b1); add8(acc[2], b2); add8(acc[3], b3);
            }
            if (j < re) {
                int s0 = ci[j] - g0;
                const unsigned short* h0 = &hW[s0 * PITCH + lh * 8];
                add8(acc[0], *(const uint4*)&h0[0]);
                add8(acc[1], *(const uint4*)&h0[32]);
                add8(acc[2], *(const uint4*)&h0[64]);
                add8(acc[3], *(const uint4*)&h0[96]);
            }
            bf16x8 af[4];
            #pragma unroll
            for (int ks = 0; ks < 4; ks++) af[ks] = packb8(acc[ks]);

            // ---- MFMA: 16(dst rows) x 128(out), K=128; B-frags from global (L2-hot) ----
            f32x4 cacc[8];
            #pragma unroll
            for (int n = 0; n < 8; n++) cacc[n] = (f32x4){0.f, 0.f, 0.f, 0.f};
            #pragma unroll
            for (int ks = 0; ks < 4; ks++) {
                #pragma unroll
                for (int n = 0; n < 8; n++) {
                    bf16x8 bf = *(const bf16x8*)&Wl[(size_t)(n * 16 + lr) * FD + ks * 32 + lh * 8];
                    cacc[n] = __builtin_amdgcn_mfma_f32_16x16x32_bf16(af[ks], bf, cacc[n], 0, 0, 0);
                }
            }

            // ---- epilogue: tanh((lin+b)*rdeg) -> cat ----
            float4 d4 = *(const float4*)&degs[g0 + row_m0 + lh * 4];
            float rd[4] = {__builtin_amdgcn_rcpf(d4.x), __builtin_amdgcn_rcpf(d4.y),
                           __builtin_amdgcn_rcpf(d4.z), __builtin_amdgcn_rcpf(d4.w)};
            #pragma unroll
            for (int n = 0; n < 8; n++) {
                int col = n * 16 + lr;
                float bc = bias[l * FD + col];
                #pragma unroll
                for (int r = 0; r < 4; r++) {
                    int grow = g0 + row_m0 + lh * 4 + r;
                    cat[(size_t)grow * DD + l * FD + col] = f2b(ftanh((cacc[n][r] + bc) * rd[r]));
                }
            }
        }
        __syncthreads();   // all gathers + cat stores done
        if (l < NL - 1) {  // restage hW from L2-hot cat
            #pragma unroll
            for (int i = 0; i < 8; i++) {
                int u = tid + i * 1024;
                int row = u >> 4, cu = u & 15;
                uint4 v = *(const uint4*)&cat[(size_t)(g0 + row) * DD + l * FD + cu * 8];
                *(uint4*)&hW[row * PITCH + cu * 8] = v;
            }
            __syncthreads();
        }
    }
}

// ---------------- attention scores: bf16 MFMA GEMM + fused tanh/dot-v ----------------
__global__ __launch_bounds__(256) void scores_k(
    const unsigned short* __restrict__ X,   // [TN][DD] bf16
    const unsigned short* __restrict__ Wt,  // [DD][DD] bf16, (n,k)
    const float* __restrict__ bv, const float* __restrict__ vv,
    float* __restrict__ sp)                 // [TN][8] partials
{
    __shared__ unsigned short sX[128][72];
    __shared__ unsigned short sW[128][72];
    int tid = threadIdx.x;
    int lane = tid & 63, wid = tid >> 6;
    int wm = wid >> 1, wn = wid & 1;
    int m0 = blockIdx.x * 128;
    int n0 = blockIdx.y * 128;
    int lr = lane & 15, lh = lane >> 4;

    f32x4 acc[4][4];
    #pragma unroll
    for (int mi = 0; mi < 4; mi++)
        #pragma unroll
        for (int ni = 0; ni < 4; ni++)
            acc[mi][ni] = (f32x4){0.f, 0.f, 0.f, 0.f};

    for (int k0 = 0; k0 < DD; k0 += 64) {
        __syncthreads();
        #pragma unroll
        for (int i = 0; i < 4; i++) {
            int idx = tid + i * 256;
            int row = idx >> 3, ch = idx & 7;
            *(float4*)&sX[row][ch * 8] = *(const float4*)&X[(size_t)(m0 + row) * DD + k0 + ch * 8];
            *(float4*)&sW[row][ch * 8] = *(const float4*)&Wt[(size_t)(n0 + row) * DD + k0 + ch * 8];
        }
        __syncthreads();
        #pragma unroll
        for (int kk = 0; kk < 64; kk += 32) {
            bf16x8 af[4], bfr[4];
            #pragma unroll
            for (int mi = 0; mi < 4; mi++)
                af[mi] = *(const bf16x8*)&sX[wm * 64 + mi * 16 + lr][kk + lh * 8];
            #pragma unroll
            for (int ni = 0; ni < 4; ni++)
                bfr[ni] = *(const bf16x8*)&sW[wn * 64 + ni * 16 + lr][kk + lh * 8];
            #pragma unroll
            for (int mi = 0; mi < 4; mi++)
                #pragma unroll
                for (int ni = 0; ni < 4; ni++)
                    acc[mi][ni] = __builtin_amdgcn_mfma_f32_16x16x32_bf16(
                        af[mi], bfr[ni], acc[mi][ni], 0, 0, 0);
        }
    }

    float vcol[4], bcol[4];
    #pragma unroll
    for (int ni = 0; ni < 4; ni++) {
        int col = n0 + wn * 64 + ni * 16 + lr;
        vcol[ni] = vv[col];
        bcol[ni] = bv[col];
    }
    #pragma unroll
    for (int mi = 0; mi < 4; mi++) {
        #pragma unroll
        for (int r = 0; r < 4; r++) {
            float part = 0.f;
            #pragma unroll
            for (int ni = 0; ni < 4; ni++)
                part += ftanh(acc[mi][ni][r] + bcol[ni]) * vcol[ni];
            part += __shfl_xor(part, 1);
            part += __shfl_xor(part, 2);
            part += __shfl_xor(part, 4);
            part += __shfl_xor(part, 8);
            if (lr == 0) {
                int row = m0 + wm * 64 + mi * 16 + lh * 4 + r;
                sp[(size_t)row * 8 + blockIdx.y * 2 + wn] = part;
            }
        }
    }
}

// ---------------- softmax + pool (one block per batch) ----------------
__global__ __launch_bounds__(256) void pool_k(
    const float* __restrict__ sp, const unsigned short* __restrict__ X,
    float* __restrict__ pooled)
{
    __shared__ float sattn[512];
    __shared__ float wred[8];
    int b = blockIdx.x, t = threadIdx.x;
    float s0, s1;
    {
        const float4* p = (const float4*)&sp[((size_t)b * NN + t) * 8];
        float4 x = p[0], y = p[1];
        s0 = x.x + x.y + x.z + x.w + y.x + y.y + y.z + y.w;
        p = (const float4*)&sp[((size_t)b * NN + 256 + t) * 8];
        x = p[0]; y = p[1];
        s1 = x.x + x.y + x.z + x.w + y.x + y.y + y.z + y.w;
    }
    float m = fmaxf(s0, s1);
    #pragma unroll
    for (int off = 1; off < 64; off <<= 1) m = fmaxf(m, __shfl_xor(m, off));
    int wid = t >> 6, lane = t & 63;
    if (lane == 0) wred[wid] = m;
    __syncthreads();
    m = fmaxf(fmaxf(wred[0], wred[1]), fmaxf(wred[2], wred[3]));
    float e0 = expf(s0 - m), e1 = expf(s1 - m);
    float ssum = e0 + e1;
    #pragma unroll
    for (int off = 1; off < 64; off <<= 1) ssum += __shfl_xor(ssum, off);
    if (lane == 0) wred[4 + wid] = ssum;
    __syncthreads();
    float inv = 1.0f / (wred[4] + wred[5] + wred[6] + wred[7]);
    sattn[t] = e0 * inv;
    sattn[t + 256] = e1 * inv;
    __syncthreads();
    float2 acc = {0.f, 0.f};
    const unsigned short* Xb = X + (size_t)b * NN * DD;
    #pragma unroll 4
    for (int n = 0; n < NN; n++) {
        float a = sattn[n];
        unsigned int px = *(const unsigned int*)&Xb[(size_t)n * DD + t * 2];
        acc.x += a * b2f(px & 0xffff);
        acc.y += a * b2f(px >> 16);
    }
    pooled[b * DD + t * 2 + 0] = acc.x;
    pooled[b * DD + t * 2 + 1] = acc.y;
}

// ---------------- output layer ----------------
__global__ void out_k(const float* __restrict__ pooled, const float* __restrict__ Wo,
                      const float* __restrict__ bo, float* __restrict__ out) {
    int b = blockIdx.x, c = threadIdx.x;  // 128 threads
    float acc = 0.f;
    const float* p = pooled + b * DD;
    for (int k = 0; k < DD; k++) acc += p[k] * Wo[k * 128 + c];
    out[b * 128 + c] = fmaxf(acc + bo[c], 0.f);
}

extern "C" void kernel_launch(void* const* d_in, const int* in_sizes, int n_in,
                              void* d_out, int out_size, void* d_ws, size_t ws_size,
                              hipStream_t stream)
{
    const float* node_feat = (const float*)d_in[0];
    const int*   edge_src  = (const int*)d_in[1];
    const int*   edge_dst  = (const int*)d_in[2];
    const float* conv_W    = (const float*)d_in[3];
    const float* conv_b    = (const float*)d_in[4];
    const float* att_W     = (const float*)d_in[5];
    const float* att_b     = (const float*)d_in[6];
    const float* att_v     = (const float*)d_in[7];
    const float* out_W     = (const float*)d_in[8];
    const float* out_b     = (const float*)d_in[9];
    float* out = (float*)d_out;
    (void)in_sizes; (void)n_in; (void)out_size;

    char* ws = (char*)d_ws;
    size_t off = 0;
    auto alloc = [&](size_t bytes) {
        void* p = ws + off;
        off += (bytes + 255) & ~(size_t)255;
        return p;
    };
    unsigned short* cat   = (unsigned short*)alloc((size_t)TN * DD * 2);  // bf16
    int*   counts  = (int*)alloc((size_t)TN * 4);
    int*   row_ptr = (int*)alloc((size_t)(TN + 1) * 4);
    int*   cursor  = (int*)alloc((size_t)TN * 4);
    int*   col_idx = (int*)alloc((size_t)NE * 4);
    float* degs    = (float*)alloc((size_t)TN * 4);
    float* sp      = (float*)alloc((size_t)TN * 8 * 4);
    unsigned short* attWt = (unsigned short*)alloc((size_t)DD * DD * 2);  // bf16
    unsigned short* convWt = (unsigned short*)alloc((size_t)NL * FD * FD * 2);
    float* pooled  = (float*)alloc((size_t)NB * DD * 4);
    if (off > ws_size) return;  // diagnostic guard

    hipMemsetAsync(counts, 0, (size_t)TN * 4, stream);
    count_k<<<NE / 256, 256, 0, stream>>>(edge_dst, counts);
    scan_b_k<<<NB, 512, 0, stream>>>(counts, row_ptr, cursor, degs);
    fill_k<<<NE / 256, 256, 0, stream>>>(edge_src, edge_dst, cursor, col_idx);
    transpose_cast_k<<<dim3(DD / 32, DD / 32), 256, 0, stream>>>(att_W, attWt);
    transp_convW_k<<<dim3(FD / 32, FD / 32, NL), 256, 0, stream>>>(conv_W, convWt);

    conv_all_k<<<NB, 1024, 0, stream>>>(node_feat, convWt, conv_b,
                                        row_ptr, col_idx, degs, cat);

    scores_k<<<dim3(TN / 128, DD / 128), 256, 0, stream>>>(cat, attWt, att_b, att_v, sp);
    pool_k<<<NB, 256, 0, stream>>>(sp, cat, pooled);
    out_k<<<NB, 128, 0, stream>>>(pooled, out_W, out_b, out);
}